// Round 22
// baseline (101.370 us; speedup 1.0000x reference)
//
#include <hip/hip_runtime.h>
#include <hip/hip_fp16.h>
#include <math.h>

#define N_NODES 12000
#define C 128
#define NEDGE 192000
#define BW 384  // u32 words per dedup bitset (12288 bits >= 12000)
#define MSK 0x7FFFFFFF
#define ELL 64  // ELL row stride; max degree ~45 (Binom(192000,1/12000)), P(>64)~1e-20

// acc_lo += s*(float)f16_lo(u); acc_hi += s*(float)f16_hi(u)  -- one VOP3P each
__device__ __forceinline__ void fmix2(float& lo, float& hi, unsigned u, float s) {
    asm("v_fma_mix_f32 %0, %2, %3, %0 op_sel:[0,0,0] op_sel_hi:[1,0,0]\n\t"
        "v_fma_mix_f32 %1, %2, %3, %1 op_sel:[1,0,0] op_sel_hi:[1,0,0]"
        : "+v"(lo), "+v"(hi)
        : "v"(u), "v"(s));
}

// acc += a.lo*b.lo + a.hi*b.hi  (f16 pairs, f32 accumulate) -- one VOP3P
__device__ __forceinline__ void dot2acc(float& acc, unsigned a, unsigned b) {
    asm("v_dot2_f32_f16 %0, %1, %2, %0" : "+v"(acc) : "v"(a), "v"(b));
}

__device__ __forceinline__ unsigned packh2(float lo, float hi) {
    __half2 h = __floats2half2_rn(lo, hi);
    return *reinterpret_cast<unsigned*>(&h);
}

#define ACCM(p, u)                                            \
    fmix2(p##0, p##1, u.x, one); fmix2(p##2, p##3, u.y, one); \
    fmix2(p##4, p##5, u.z, one); fmix2(p##6, p##7, u.w, one)

#define RED2(x) x += __shfl_xor(x, 16); x += __shfl_xor(x, 32)

// ---- zero deg[12288] (12 blocks * 256 * int4 = 49152 B) ----
__global__ __launch_bounds__(256) void clear_ws(int4* __restrict__ p) {
    p[blockIdx.x * 256 + threadIdx.x] = int4{0, 0, 0, 0};
}

// ---- merged: x->f16 + ELL edge scatter (blocks 0..2999) | weight fuse+pack (3000..3127) ----
// Weight layout Wq*: uint4 at (t*256 + c0*2) = { (k2,c0), (k2+1,c0), (k2,c0+1), (k2+1,c0+1) }, k2 = 2t.
__global__ __launch_bounds__(256) void prep_fuse(const float* __restrict__ x,
                                                 unsigned* __restrict__ xbu,
                                                 const int* __restrict__ ei,
                                                 int* __restrict__ deg,
                                                 int* __restrict__ col,
                                                 const float* __restrict__ W1,
                                                 const float* __restrict__ W2,
                                                 const float* __restrict__ Wg,
                                                 const float* __restrict__ b1,
                                                 const float* __restrict__ b2,
                                                 const float* __restrict__ bg,
                                                 unsigned* __restrict__ Wq1,
                                                 unsigned* __restrict__ Wq2,
                                                 unsigned* __restrict__ Wqf1,
                                                 unsigned* __restrict__ Wqf2,
                                                 float* __restrict__ bfused) {
    const int tid = threadIdx.x;
    if (blockIdx.x < 3000) {
        int g = blockIdx.x * 256 + tid;
        if (g < N_NODES * C / 2) {
            unsigned pa = __half_as_ushort(__float2half(x[2 * g]));
            unsigned pb = __half_as_ushort(__float2half(x[2 * g + 1]));
            xbu[g] = pa | (pb << 16);
        }
        if (g < NEDGE) {
            int s = ei[g];
            int t = ei[NEDGE + g];
            int pos = atomicAdd(&deg[s], 1);
            col[(s << 6) + pos] = t;
        }
        return;
    }
    __shared__ __align__(16) float wg1[C];
    __shared__ __align__(16) float wg2[C];
    __shared__ float sb[C];
    __shared__ float l1[C], l2[C], lf1[C], lf2[C];
    const int c = blockIdx.x - 3000;
    const int j = tid;
    if (j < 128) {
        float g1 = Wg[(size_t)j * C + c];
        float g2 = Wg[(size_t)(C + j) * C + c];
        wg1[j] = g1;
        wg2[j] = g2;
        sb[j] = b1[j] * g1 + b2[j] * g2;
    }
    __syncthreads();
    if (j < 128) {
        float s1 = 0.f, s2 = 0.f;
        for (int k = 0; k < C; k += 4) {
            float4 a = *(const float4*)&W1[(size_t)j * C + k];
            float4 b = *(const float4*)&W2[(size_t)j * C + k];
            float4 u = *(const float4*)&wg1[k];
            float4 v = *(const float4*)&wg2[k];
            s1 += a.x * u.x + a.y * u.y + a.z * u.z + a.w * u.w;
            s2 += b.x * v.x + b.y * v.y + b.z * v.z + b.w * v.w;
        }
        l1[j] = W1[(size_t)j * C + c];
        l2[j] = W2[(size_t)j * C + c];
        lf1[j] = s1;
        lf2[j] = s2;
    }
    __syncthreads();
    if (j < 64) {   // j = k-pair index; t = j>>1 groups two k-pairs, u = j&1
        const int t = j >> 1, u = j & 1;
        const int o = t * 256 + c * 2 + u;
        Wq1[o]  = packh2(l1[2 * j], l1[2 * j + 1]);
        Wq2[o]  = packh2(l2[2 * j], l2[2 * j + 1]);
        Wqf1[o] = packh2(lf1[2 * j], lf1[2 * j + 1]);
        Wqf2[o] = packh2(lf2[2 * j], lf2[2 * j + 1]);
    }
    if (j == 0) {
        float s = bg[c];
        for (int k = 0; k < C; ++k) s += sb[k];
        bfused[c] = s;
    }
}

// ---- mark dup edges (sign bit) + h(dedup, f16) + agg1(multiplicity, f16 packed) ----
__global__ __launch_bounds__(256) void markdup_h(const int* __restrict__ deg,
                                                 int* __restrict__ col,
                                                 const unsigned* __restrict__ xb,
                                                 unsigned* __restrict__ hb,
                                                 unsigned* __restrict__ agg1p) {
    __shared__ int rows[4][ELL];
    const int tid = threadIdx.x;
    const int lane = tid & 63, wv = tid >> 6;
    const int i = blockIdx.x * 4 + wv;
    const int rb = i << 6;
    const int d = deg[i];
    const uint4* xb4 = (const uint4*)xb;
    const float one = 1.0f;

    if (lane < d) rows[wv][lane] = col[rb + lane];
    if (lane < d) {
        int vm = rows[wv][lane] & MSK;
        bool dup = false;
        for (int e2 = 0; e2 < lane; ++e2)
            if ((rows[wv][e2] & MSK) == vm) { dup = true; break; }
        if (dup) {
            rows[wv][lane] = vm | 0x80000000;
            col[rb + lane] = vm | 0x80000000;   // visible to next dispatch
        }
    }
    __syncthreads();

    const int g = lane >> 4, l16 = lane & 15;
    float a0 = 0, a1 = 0, a2 = 0, a3 = 0, a4 = 0, a5 = 0, a6 = 0, a7 = 0;
    float b0 = 0, b1 = 0, b2 = 0, b3 = 0, b4 = 0, b5 = 0, b6 = 0, b7 = 0;
    for (int e = g; e < d; e += 4) {
        int c0 = rows[wv][e];
        int k = c0 & MSK;
        uint4 u = xb4[(unsigned)((k << 4) | l16)];
        ACCM(b, u);
        if (c0 >= 0) { ACCM(a, u); }
    }
    RED2(a0); RED2(a1); RED2(a2); RED2(a3); RED2(a4); RED2(a5); RED2(a6); RED2(a7);
    RED2(b0); RED2(b1); RED2(b2); RED2(b3); RED2(b4); RED2(b5); RED2(b6); RED2(b7);
    if (lane < 16) {
        uint4 hp = {packh2(a0, a1), packh2(a2, a3), packh2(a4, a5), packh2(a6, a7)};
        ((uint4*)hb)[(unsigned)((i << 4) | l16)] = hp;
        uint4 ap = {packh2(b0, b1), packh2(b2, b3), packh2(b4, b5), packh2(b6, b7)};
        ((uint4*)agg1p)[(unsigned)((i << 4) | l16)] = ap;
    }
}

// ---- merged twohop + epilogue: 750 blocks x 4 waves; wave wv owns rows wv*4..+3.
//      agg2 lives only in LDS (shB). ZERO barriers: all LDS is same-wave produce/consume. ----
__global__ __launch_bounds__(256) void twohop_epi(const int* __restrict__ deg,
                                                  const int* __restrict__ col,
                                                  const unsigned* __restrict__ xb,
                                                  const unsigned* __restrict__ hb,
                                                  const unsigned* __restrict__ agg1p,
                                                  const unsigned* __restrict__ Wq1,
                                                  const unsigned* __restrict__ Wq2,
                                                  const unsigned* __restrict__ Wqf1,
                                                  const unsigned* __restrict__ Wqf2,
                                                  const float* __restrict__ b1,
                                                  const float* __restrict__ b2,
                                                  const float* __restrict__ bfused,
                                                  float* __restrict__ out) {
    __shared__ unsigned accS[4][BW];          // 6 KB: per-wave dedup bitset
    __shared__ int jrowS[4][64];              // 1 KB: per-wave row cache
    __shared__ unsigned short corrS[4][128];  // 1 KB: per-wave corrections
    __shared__ int ncS[4];
    __shared__ unsigned shA[16][64];          // 4 KB: agg1 (f16 packed)
    __shared__ unsigned shB[16][64];          // 4 KB: agg2 (f16 packed, never leaves LDS)
    const int tid = threadIdx.x;
    const int lane = tid & 63, wv = tid >> 6;
    const int r0 = blockIdx.x * 16;
    unsigned* acc = accS[wv];
    unsigned short* corr = corrS[wv];
    const uint4* xb4 = (const uint4*)xb;
    const uint4* hb4 = (const uint4*)hb;
    const float one = 1.0f, neg1 = -1.0f;
    const int g = lane >> 4, l16 = lane & 15;

    // ---- phase 1: per-wave, 4 nodes sequentially (verbatim R21 twohop body) ----
    for (int n = 0; n < 4; ++n) {
        const int i = r0 + (wv << 2) + n;
        const int rb = i << 6;
        const int d = deg[i];
#pragma unroll
        for (int m = 0; m < 6; ++m) acc[lane + (m << 6)] = 0u;
        if (lane == 0) ncS[wv] = 0;

        int j = -1, len = 0;
        if (lane < d) {
            j = col[rb + lane];
            if (j >= 0) len = deg[j];
        }
        jrowS[wv][lane] = j;
        const int jb = (j >= 0) ? (j << 6) : 0;
        int p = len;
#pragma unroll
        for (int dd = 1; dd < 64; dd <<= 1) {
            int u = __shfl_up(p, dd);
            if (lane >= dd) p += u;
        }
        const int myPos = p - len;
        const int total = __shfl(p, 63);

        for (int q0 = 0; q0 < total; q0 += 64) {
            const int q = q0 + lane;
            const int qc = (q < total) ? q : (total - 1);
            int lo = 0, hi = d - 1;
#pragma unroll
            for (int it = 0; it < 6; ++it) {
                int mid = (lo + hi + 1) >> 1;
                int sp = __shfl(myPos, mid);
                if (lo < hi) { if (sp <= qc) lo = mid; else hi = mid - 1; }
            }
            const int base = __shfl(jb, lo);
            const int pos0 = __shfl(myPos, lo);
            if (q < total) {
                int t = col[base + (qc - pos0)];
                if (t >= 0) {
                    unsigned bit = 1u << (t & 31);
                    unsigned old = atomicOr(&acc[t >> 5], bit);
                    if (old & bit) {
                        int pc = atomicAdd(&ncS[wv], 1);
                        if (pc < 128) corr[pc] = (unsigned short)t;
                    }
                }
            }
        }
        if (lane == 0) {
            if (acc[i >> 5] & (1u << (i & 31))) {
                int pc = atomicAdd(&ncS[wv], 1);
                if (pc < 128) corr[pc] = (unsigned short)i;
            }
        }

        float a0 = 0, a1 = 0, a2 = 0, a3 = 0, a4 = 0, a5 = 0, a6 = 0, a7 = 0;
        for (int e = g; e < d; e += 4) {
            int t = jrowS[wv][e];
            if (t >= 0) {
                uint4 u = hb4[(unsigned)((t << 4) | l16)];
                ACCM(a, u);
            }
        }
        {
            int nc = ncS[wv];
            if (nc > 128) nc = 128;
            for (int q = g; q < nc; q += 4) {
                int t = corr[q];
                uint4 u = xb4[(unsigned)((t << 4) | l16)];
                fmix2(a0, a1, u.x, neg1);
                fmix2(a2, a3, u.y, neg1);
                fmix2(a4, a5, u.z, neg1);
                fmix2(a6, a7, u.w, neg1);
            }
        }
        RED2(a0); RED2(a1); RED2(a2); RED2(a3); RED2(a4); RED2(a5); RED2(a6); RED2(a7);
        if (lane < 16) {
            uint4 ap = {packh2(a0, a1), packh2(a2, a3), packh2(a4, a5), packh2(a6, a7)};
            ((uint4*)shB[(wv << 2) + n])[l16] = ap;
        }
    }

    // ---- stage shA rows wv*4..wv*4+3 (same-wave produce/consume; no barrier) ----
    {
        const int r = (wv << 2) + (lane >> 4);
        const int q4 = lane & 15;
        ((uint4*)shA[r])[q4] = ((const uint4*)agg1p)[(unsigned)(((r0 + r) << 4) | q4)];
    }

    // ---- phase 2: epilogue (verbatim R21), rg = wv*4, c0 = lane*2 ----
    const int c0 = lane * 2;
    const int rg = wv << 2;
    float z1v[4][2] = {}, z2v[4][2] = {}, gv[4][2] = {};
    const int wbase = c0 * 2;
    for (int t = 0; t < 32; ++t) {
        uint4 W1q = *(const uint4*)&Wq1[t * 256 + wbase];
        uint4 W2q = *(const uint4*)&Wq2[t * 256 + wbase];
        uint4 F1q = *(const uint4*)&Wqf1[t * 256 + wbase];
        uint4 F2q = *(const uint4*)&Wqf2[t * 256 + wbase];
        const int k2 = t * 2;
#pragma unroll
        for (int r = 0; r < 4; ++r) {
            uint2 aA = *(const uint2*)&shA[rg + r][k2];
            uint2 aB = *(const uint2*)&shB[rg + r][k2];
            dot2acc(z1v[r][0], aA.x, W1q.x); dot2acc(z1v[r][0], aA.y, W1q.y);
            dot2acc(z1v[r][1], aA.x, W1q.z); dot2acc(z1v[r][1], aA.y, W1q.w);
            dot2acc(z2v[r][0], aB.x, W2q.x); dot2acc(z2v[r][0], aB.y, W2q.y);
            dot2acc(z2v[r][1], aB.x, W2q.z); dot2acc(z2v[r][1], aB.y, W2q.w);
            dot2acc(gv[r][0], aA.x, F1q.x);  dot2acc(gv[r][0], aA.y, F1q.y);
            dot2acc(gv[r][1], aA.x, F1q.z);  dot2acc(gv[r][1], aA.y, F1q.w);
            dot2acc(gv[r][0], aB.x, F2q.x);  dot2acc(gv[r][0], aB.y, F2q.y);
            dot2acc(gv[r][1], aB.x, F2q.z);  dot2acc(gv[r][1], aB.y, F2q.w);
        }
    }
    const float2 b1v = *(const float2*)&b1[c0];
    const float2 b2v = *(const float2*)&b2[c0];
    const float2 bfv = *(const float2*)&bfused[c0];
#pragma unroll
    for (int r = 0; r < 4; ++r) {
        float g0 = 1.f / (1.f + expf(-(gv[r][0] + bfv.x)));
        float g1 = 1.f / (1.f + expf(-(gv[r][1] + bfv.y)));
        float2 res;
        res.x = g0 * (z1v[r][0] + b1v.x) + (1.f - g0) * (z2v[r][0] + b2v.x);
        res.y = g1 * (z1v[r][1] + b1v.y) + (1.f - g1) * (z2v[r][1] + b2v.y);
        *(float2*)&out[(size_t)(r0 + rg + r) * C + c0] = res;
    }
}

extern "C" void kernel_launch(void* const* d_in, const int* in_sizes, int n_in,
                              void* d_out, int out_size, void* d_ws, size_t ws_size,
                              hipStream_t stream) {
    const float* x  = (const float*)d_in[0];
    const int*   ei = (const int*)d_in[1];
    const float* W1 = (const float*)d_in[2];
    const float* b1 = (const float*)d_in[3];
    const float* W2 = (const float*)d_in[4];
    const float* b2 = (const float*)d_in[5];
    const float* Wg = (const float*)d_in[6];
    const float* bg = (const float*)d_in[7];
    float* out = (float*)d_out;

    char* ws = (char*)d_ws;
    size_t o = 0;
    auto alloc = [&](size_t bytes) { char* p = ws + o; o = (o + bytes + 255) & ~(size_t)255; return p; };
    int* col      = (int*)alloc((size_t)N_NODES * ELL * 4);       // 3 MB ELL
    int* deg      = (int*)alloc((size_t)12288 * 4);               // cleared region (49152 B)
    unsigned* xb  = (unsigned*)alloc((size_t)N_NODES * C * 2);    // f16 x
    unsigned* hb  = (unsigned*)alloc((size_t)N_NODES * C * 2);    // f16 h = Adj_bin@x
    unsigned* agg1p = (unsigned*)alloc((size_t)N_NODES * C * 2);  // f16 packed agg1
    unsigned* Wq1  = (unsigned*)alloc((size_t)(C / 2) * C * 4);
    unsigned* Wq2  = (unsigned*)alloc((size_t)(C / 2) * C * 4);
    unsigned* Wqf1 = (unsigned*)alloc((size_t)(C / 2) * C * 4);
    unsigned* Wqf2 = (unsigned*)alloc((size_t)(C / 2) * C * 4);
    float* bfused  = (float*)alloc((size_t)C * 4);
    // total ~12.7 MB (proven safe)

    clear_ws<<<12, 256, 0, stream>>>((int4*)deg);
    prep_fuse<<<3128, 256, 0, stream>>>(x, xb, ei, deg, col, W1, W2, Wg, b1, b2, bg,
                                        Wq1, Wq2, Wqf1, Wqf2, bfused);
    markdup_h<<<N_NODES / 4, 256, 0, stream>>>(deg, col, xb, hb, agg1p);
    twohop_epi<<<N_NODES / 16, 256, 0, stream>>>(deg, col, xb, hb, agg1p,
                                                 Wq1, Wq2, Wqf1, Wqf2,
                                                 b1, b2, bfused, out);
}

// Round 23
// 95.173 us; speedup vs baseline: 1.0651x; 1.0651x over previous
//
#include <hip/hip_runtime.h>
#include <hip/hip_fp16.h>
#include <math.h>

#define N_NODES 12000
#define C 128
#define NEDGE 192000
#define BW 384  // u32 words per dedup bitset (12288 bits >= 12000)
#define MSK 0x7FFFFFFF
#define ELL 64  // ELL row stride; max degree ~45 (Binom(192000,1/12000)), P(>64)~1e-20

// acc_lo += s*(float)f16_lo(u); acc_hi += s*(float)f16_hi(u)  -- one VOP3P each
__device__ __forceinline__ void fmix2(float& lo, float& hi, unsigned u, float s) {
    asm("v_fma_mix_f32 %0, %2, %3, %0 op_sel:[0,0,0] op_sel_hi:[1,0,0]\n\t"
        "v_fma_mix_f32 %1, %2, %3, %1 op_sel:[1,0,0] op_sel_hi:[1,0,0]"
        : "+v"(lo), "+v"(hi)
        : "v"(u), "v"(s));
}

// acc += a.lo*b.lo + a.hi*b.hi  (f16 pairs, f32 accumulate) -- one VOP3P
__device__ __forceinline__ void dot2acc(float& acc, unsigned a, unsigned b) {
    asm("v_dot2_f32_f16 %0, %1, %2, %0" : "+v"(acc) : "v"(a), "v"(b));
}

__device__ __forceinline__ unsigned packh2(float lo, float hi) {
    __half2 h = __floats2half2_rn(lo, hi);
    return *reinterpret_cast<unsigned*>(&h);
}

#define ACCM(p, u)                                            \
    fmix2(p##0, p##1, u.x, one); fmix2(p##2, p##3, u.y, one); \
    fmix2(p##4, p##5, u.z, one); fmix2(p##6, p##7, u.w, one)

#define RED2(x) x += __shfl_xor(x, 16); x += __shfl_xor(x, 32)

// ---- zero deg[12288] (12 blocks * 256 * int4 = 49152 B) ----
__global__ __launch_bounds__(256) void clear_ws(int4* __restrict__ p) {
    p[blockIdx.x * 256 + threadIdx.x] = int4{0, 0, 0, 0};
}

// ---- merged: x->f16 + ELL edge scatter (blocks 0..2999) | weight fuse+pack (3000..3127) ----
// Weight layout Wq*: uint4 at (t*256 + c0*2) = { (k2,c0), (k2+1,c0), (k2,c0+1), (k2+1,c0+1) }, k2 = 2t.
__global__ __launch_bounds__(256) void prep_fuse(const float* __restrict__ x,
                                                 unsigned* __restrict__ xbu,
                                                 const int* __restrict__ ei,
                                                 int* __restrict__ deg,
                                                 int* __restrict__ col,
                                                 const float* __restrict__ W1,
                                                 const float* __restrict__ W2,
                                                 const float* __restrict__ Wg,
                                                 const float* __restrict__ b1,
                                                 const float* __restrict__ b2,
                                                 const float* __restrict__ bg,
                                                 unsigned* __restrict__ Wq1,
                                                 unsigned* __restrict__ Wq2,
                                                 unsigned* __restrict__ Wqf1,
                                                 unsigned* __restrict__ Wqf2,
                                                 float* __restrict__ bfused) {
    const int tid = threadIdx.x;
    if (blockIdx.x < 3000) {
        int g = blockIdx.x * 256 + tid;
        if (g < N_NODES * C / 2) {
            unsigned pa = __half_as_ushort(__float2half(x[2 * g]));
            unsigned pb = __half_as_ushort(__float2half(x[2 * g + 1]));
            xbu[g] = pa | (pb << 16);
        }
        if (g < NEDGE) {
            int s = ei[g];
            int t = ei[NEDGE + g];
            int pos = atomicAdd(&deg[s], 1);
            col[(s << 6) + pos] = t;
        }
        return;
    }
    __shared__ __align__(16) float wg1[C];
    __shared__ __align__(16) float wg2[C];
    __shared__ float sb[C];
    __shared__ float l1[C], l2[C], lf1[C], lf2[C];
    const int c = blockIdx.x - 3000;
    const int j = tid;
    if (j < 128) {
        float g1 = Wg[(size_t)j * C + c];
        float g2 = Wg[(size_t)(C + j) * C + c];
        wg1[j] = g1;
        wg2[j] = g2;
        sb[j] = b1[j] * g1 + b2[j] * g2;
    }
    __syncthreads();
    if (j < 128) {
        float s1 = 0.f, s2 = 0.f;
        for (int k = 0; k < C; k += 4) {
            float4 a = *(const float4*)&W1[(size_t)j * C + k];
            float4 b = *(const float4*)&W2[(size_t)j * C + k];
            float4 u = *(const float4*)&wg1[k];
            float4 v = *(const float4*)&wg2[k];
            s1 += a.x * u.x + a.y * u.y + a.z * u.z + a.w * u.w;
            s2 += b.x * v.x + b.y * v.y + b.z * v.z + b.w * v.w;
        }
        l1[j] = W1[(size_t)j * C + c];
        l2[j] = W2[(size_t)j * C + c];
        lf1[j] = s1;
        lf2[j] = s2;
    }
    __syncthreads();
    if (j < 64) {   // j = k-pair index; t = j>>1 groups two k-pairs, u = j&1
        const int t = j >> 1, u = j & 1;
        const int o = t * 256 + c * 2 + u;
        Wq1[o]  = packh2(l1[2 * j], l1[2 * j + 1]);
        Wq2[o]  = packh2(l2[2 * j], l2[2 * j + 1]);
        Wqf1[o] = packh2(lf1[2 * j], lf1[2 * j + 1]);
        Wqf2[o] = packh2(lf2[2 * j], lf2[2 * j + 1]);
    }
    if (j == 0) {
        float s = bg[c];
        for (int k = 0; k < C; ++k) s += sb[k];
        bfused[c] = s;
    }
}

// ---- mark dup edges (sign bit) + h(dedup, f16) + agg1(multiplicity, f16 packed) ----
__global__ __launch_bounds__(256) void markdup_h(const int* __restrict__ deg,
                                                 int* __restrict__ col,
                                                 const unsigned* __restrict__ xb,
                                                 unsigned* __restrict__ hb,
                                                 unsigned* __restrict__ agg1p) {
    __shared__ int rows[4][ELL];
    const int tid = threadIdx.x;
    const int lane = tid & 63, wv = tid >> 6;
    const int i = blockIdx.x * 4 + wv;
    const int rb = i << 6;
    const int d = deg[i];
    const uint4* xb4 = (const uint4*)xb;
    const float one = 1.0f;

    if (lane < d) rows[wv][lane] = col[rb + lane];
    if (lane < d) {
        int vm = rows[wv][lane] & MSK;
        bool dup = false;
        for (int e2 = 0; e2 < lane; ++e2)
            if ((rows[wv][e2] & MSK) == vm) { dup = true; break; }
        if (dup) {
            rows[wv][lane] = vm | 0x80000000;
            col[rb + lane] = vm | 0x80000000;   // visible to next dispatch
        }
    }
    __syncthreads();

    const int g = lane >> 4, l16 = lane & 15;
    float a0 = 0, a1 = 0, a2 = 0, a3 = 0, a4 = 0, a5 = 0, a6 = 0, a7 = 0;
    float b0 = 0, b1 = 0, b2 = 0, b3 = 0, b4 = 0, b5 = 0, b6 = 0, b7 = 0;
    for (int e = g; e < d; e += 4) {
        int c0 = rows[wv][e];
        int k = c0 & MSK;
        uint4 u = xb4[(unsigned)((k << 4) | l16)];
        ACCM(b, u);
        if (c0 >= 0) { ACCM(a, u); }
    }
    RED2(a0); RED2(a1); RED2(a2); RED2(a3); RED2(a4); RED2(a5); RED2(a6); RED2(a7);
    RED2(b0); RED2(b1); RED2(b2); RED2(b3); RED2(b4); RED2(b5); RED2(b6); RED2(b7);
    if (lane < 16) {
        uint4 hp = {packh2(a0, a1), packh2(a2, a3), packh2(a4, a5), packh2(a6, a7)};
        ((uint4*)hb)[(unsigned)((i << 4) | l16)] = hp;
        uint4 ap = {packh2(b0, b1), packh2(b2, b3), packh2(b4, b5), packh2(b6, b7)};
        ((uint4*)agg1p)[(unsigned)((i << 4) | l16)] = ap;
    }
}

// ---- wave-per-node: union + corrections + agg2(f16 packed) = Adj_bin@h - corr. ----
__global__ __launch_bounds__(256) void twohop_fused(const int* __restrict__ deg,
                                                    const int* __restrict__ col,
                                                    const unsigned* __restrict__ xb,
                                                    const unsigned* __restrict__ hb,
                                                    unsigned* __restrict__ agg2p) {
    __shared__ unsigned accS[4][BW];          // 6 KB: per-wave dedup bitset
    __shared__ int jrowS[4][64];              // 1 KB: per-wave row cache
    __shared__ unsigned short corrS[4][128];  // 1 KB: per-wave corrections
    __shared__ int ncS[4];
    const int tid = threadIdx.x;
    const int lane = tid & 63, wv = tid >> 6;
    const int i = blockIdx.x * 4 + wv;
    unsigned* acc = accS[wv];
    unsigned short* corr = corrS[wv];
    const int rb = i << 6;
    const int d = deg[i];
    const uint4* xb4 = (const uint4*)xb;
    const uint4* hb4 = (const uint4*)hb;
    const float one = 1.0f, neg1 = -1.0f;

#pragma unroll
    for (int m = 0; m < 6; ++m) acc[lane + (m << 6)] = 0u;
    if (lane == 0) ncS[wv] = 0;

    int j = -1, len = 0;
    if (lane < d) {
        j = col[rb + lane];
        if (j >= 0) len = deg[j];
    }
    jrowS[wv][lane] = j;                   // LDS cache: divergence-safe reads later
    const int jb = (j >= 0) ? (j << 6) : 0;
    int p = len;
#pragma unroll
    for (int dd = 1; dd < 64; dd <<= 1) {
        int u = __shfl_up(p, dd);
        if (lane >= dd) p += u;
    }
    const int myPos = p - len;
    const int total = __shfl(p, 63);

    // flattened candidates: UNIFORM trip count; all lanes execute every shfl
    for (int q0 = 0; q0 < total; q0 += 64) {
        const int q = q0 + lane;
        const int qc = (q < total) ? q : (total - 1);
        int lo = 0, hi = d - 1;
#pragma unroll
        for (int it = 0; it < 6; ++it) {
            int mid = (lo + hi + 1) >> 1;
            int sp = __shfl(myPos, mid);
            if (lo < hi) { if (sp <= qc) lo = mid; else hi = mid - 1; }
        }
        const int base = __shfl(jb, lo);
        const int pos0 = __shfl(myPos, lo);
        if (q < total) {
            int t = col[base + (qc - pos0)];
            if (t >= 0) {
                unsigned bit = 1u << (t & 31);
                unsigned old = atomicOr(&acc[t >> 5], bit);
                if (old & bit) {
                    int pc = atomicAdd(&ncS[wv], 1);
                    if (pc < 128) corr[pc] = (unsigned short)t;
                }
            }
        }
    }
    if (lane == 0) {
        if (acc[i >> 5] & (1u << (i & 31))) {
            int pc = atomicAdd(&ncS[wv], 1);
            if (pc < 128) corr[pc] = (unsigned short)i;
        }
    }

    const int g = lane >> 4, l16 = lane & 15;
    float a0 = 0, a1 = 0, a2 = 0, a3 = 0, a4 = 0, a5 = 0, a6 = 0, a7 = 0;
    for (int e = g; e < d; e += 4) {
        int t = jrowS[wv][e];
        if (t >= 0) {
            uint4 u = hb4[(unsigned)((t << 4) | l16)];
            ACCM(a, u);
        }
    }

    {
        int nc = ncS[wv];
        if (nc > 128) nc = 128;
        for (int q = g; q < nc; q += 4) {
            int t = corr[q];
            uint4 u = xb4[(unsigned)((t << 4) | l16)];
            fmix2(a0, a1, u.x, neg1);
            fmix2(a2, a3, u.y, neg1);
            fmix2(a4, a5, u.z, neg1);
            fmix2(a6, a7, u.w, neg1);
        }
    }

    RED2(a0); RED2(a1); RED2(a2); RED2(a3); RED2(a4); RED2(a5); RED2(a6); RED2(a7);
    if (lane < 16) {
        uint4 ap = {packh2(a0, a1), packh2(a2, a3), packh2(a4, a5), packh2(a6, a7)};
        ((uint4*)agg2p)[(unsigned)((i << 4) | l16)] = ap;
    }
}

// ---- single-pass epilogue: 16 rows/block, packed agg staging + uint4 weight loads ----
__global__ __launch_bounds__(256) void epilogue(const unsigned* __restrict__ agg1p,
                                                const unsigned* __restrict__ agg2p,
                                                const unsigned* __restrict__ Wq1,
                                                const unsigned* __restrict__ Wq2,
                                                const unsigned* __restrict__ Wqf1,
                                                const unsigned* __restrict__ Wqf2,
                                                const float* __restrict__ b1,
                                                const float* __restrict__ b2,
                                                const float* __restrict__ bfused,
                                                float* __restrict__ out) {
    __shared__ unsigned shA[16][64];
    __shared__ unsigned shB[16][64];
    const int r0 = blockIdx.x * 16;
    const int tid = threadIdx.x;
    const int c0 = (tid & 63) * 2;
    const int rg = (tid >> 6) * 4;

    {   // 16 rows x 16 uint4 = 256: one per thread, straight copy (agg already f16)
        const int r = tid >> 4, q4 = tid & 15;
        ((uint4*)shA[r])[q4] = ((const uint4*)agg1p)[(unsigned)(((r0 + r) << 4) | q4)];
        ((uint4*)shB[r])[q4] = ((const uint4*)agg2p)[(unsigned)(((r0 + r) << 4) | q4)];
    }
    __syncthreads();

    float z1v[4][2] = {}, z2v[4][2] = {}, gv[4][2] = {};
    const int wbase = c0 * 2;
    for (int t = 0; t < 32; ++t) {
        uint4 W1q = *(const uint4*)&Wq1[t * 256 + wbase];   // {k2|c0, k2+1|c0, k2|c0+1, k2+1|c0+1}
        uint4 W2q = *(const uint4*)&Wq2[t * 256 + wbase];
        uint4 F1q = *(const uint4*)&Wqf1[t * 256 + wbase];
        uint4 F2q = *(const uint4*)&Wqf2[t * 256 + wbase];
        const int k2 = t * 2;
#pragma unroll
        for (int r = 0; r < 4; ++r) {
            uint2 aA = *(const uint2*)&shA[rg + r][k2];
            uint2 aB = *(const uint2*)&shB[rg + r][k2];
            dot2acc(z1v[r][0], aA.x, W1q.x); dot2acc(z1v[r][0], aA.y, W1q.y);
            dot2acc(z1v[r][1], aA.x, W1q.z); dot2acc(z1v[r][1], aA.y, W1q.w);
            dot2acc(z2v[r][0], aB.x, W2q.x); dot2acc(z2v[r][0], aB.y, W2q.y);
            dot2acc(z2v[r][1], aB.x, W2q.z); dot2acc(z2v[r][1], aB.y, W2q.w);
            dot2acc(gv[r][0], aA.x, F1q.x);  dot2acc(gv[r][0], aA.y, F1q.y);
            dot2acc(gv[r][1], aA.x, F1q.z);  dot2acc(gv[r][1], aA.y, F1q.w);
            dot2acc(gv[r][0], aB.x, F2q.x);  dot2acc(gv[r][0], aB.y, F2q.y);
            dot2acc(gv[r][1], aB.x, F2q.z);  dot2acc(gv[r][1], aB.y, F2q.w);
        }
    }
    const float2 b1v = *(const float2*)&b1[c0];
    const float2 b2v = *(const float2*)&b2[c0];
    const float2 bfv = *(const float2*)&bfused[c0];
#pragma unroll
    for (int r = 0; r < 4; ++r) {
        float g0 = 1.f / (1.f + expf(-(gv[r][0] + bfv.x)));
        float g1 = 1.f / (1.f + expf(-(gv[r][1] + bfv.y)));
        float2 res;
        res.x = g0 * (z1v[r][0] + b1v.x) + (1.f - g0) * (z2v[r][0] + b2v.x);
        res.y = g1 * (z1v[r][1] + b1v.y) + (1.f - g1) * (z2v[r][1] + b2v.y);
        *(float2*)&out[(size_t)(r0 + rg + r) * C + c0] = res;
    }
}

extern "C" void kernel_launch(void* const* d_in, const int* in_sizes, int n_in,
                              void* d_out, int out_size, void* d_ws, size_t ws_size,
                              hipStream_t stream) {
    const float* x  = (const float*)d_in[0];
    const int*   ei = (const int*)d_in[1];
    const float* W1 = (const float*)d_in[2];
    const float* b1 = (const float*)d_in[3];
    const float* W2 = (const float*)d_in[4];
    const float* b2 = (const float*)d_in[5];
    const float* Wg = (const float*)d_in[6];
    const float* bg = (const float*)d_in[7];
    float* out = (float*)d_out;

    char* ws = (char*)d_ws;
    size_t o = 0;
    auto alloc = [&](size_t bytes) { char* p = ws + o; o = (o + bytes + 255) & ~(size_t)255; return p; };
    int* col      = (int*)alloc((size_t)N_NODES * ELL * 4);       // 3 MB ELL
    int* deg      = (int*)alloc((size_t)12288 * 4);               // cleared region (49152 B)
    unsigned* xb  = (unsigned*)alloc((size_t)N_NODES * C * 2);    // f16 x
    unsigned* hb  = (unsigned*)alloc((size_t)N_NODES * C * 2);    // f16 h = Adj_bin@x
    unsigned* agg1p = (unsigned*)alloc((size_t)N_NODES * C * 2);  // f16 packed agg1
    unsigned* agg2p = (unsigned*)alloc((size_t)N_NODES * C * 2);  // f16 packed agg2
    unsigned* Wq1  = (unsigned*)alloc((size_t)(C / 2) * C * 4);
    unsigned* Wq2  = (unsigned*)alloc((size_t)(C / 2) * C * 4);
    unsigned* Wqf1 = (unsigned*)alloc((size_t)(C / 2) * C * 4);
    unsigned* Wqf2 = (unsigned*)alloc((size_t)(C / 2) * C * 4);
    float* bfused  = (float*)alloc((size_t)C * 4);
    // total ~15.7 MB (proven safe)

    clear_ws<<<12, 256, 0, stream>>>((int4*)deg);
    prep_fuse<<<3128, 256, 0, stream>>>(x, xb, ei, deg, col, W1, W2, Wg, b1, b2, bg,
                                        Wq1, Wq2, Wqf1, Wqf2, bfused);
    markdup_h<<<N_NODES / 4, 256, 0, stream>>>(deg, col, xb, hb, agg1p);
    twohop_fused<<<N_NODES / 4, 256, 0, stream>>>(deg, col, xb, hb, agg2p);
    epilogue<<<N_NODES / 16, 256, 0, stream>>>(agg1p, agg2p, Wq1, Wq2, Wqf1, Wqf2,
                                               b1, b2, bfused, out);
}

// Round 24
// 91.854 us; speedup vs baseline: 1.1036x; 1.0361x over previous
//
#include <hip/hip_runtime.h>
#include <hip/hip_fp16.h>
#include <math.h>

#define N_NODES 12000
#define C 128
#define NEDGE 192000
#define BW 384  // u32 words per dedup bitset (12288 bits >= 12000)
#define MSK 0x7FFFFFFF
#define ELL 64  // ELL row stride; max degree ~45 (Binom(192000,1/12000)), P(>64)~1e-20

// acc_lo += s*(float)f16_lo(u); acc_hi += s*(float)f16_hi(u)  -- one VOP3P each
__device__ __forceinline__ void fmix2(float& lo, float& hi, unsigned u, float s) {
    asm("v_fma_mix_f32 %0, %2, %3, %0 op_sel:[0,0,0] op_sel_hi:[1,0,0]\n\t"
        "v_fma_mix_f32 %1, %2, %3, %1 op_sel:[1,0,0] op_sel_hi:[1,0,0]"
        : "+v"(lo), "+v"(hi)
        : "v"(u), "v"(s));
}

// acc += a.lo*b.lo + a.hi*b.hi  (f16 pairs, f32 accumulate) -- one VOP3P
__device__ __forceinline__ void dot2acc(float& acc, unsigned a, unsigned b) {
    asm("v_dot2_f32_f16 %0, %1, %2, %0" : "+v"(acc) : "v"(a), "v"(b));
}

__device__ __forceinline__ unsigned packh2(float lo, float hi) {
    __half2 h = __floats2half2_rn(lo, hi);
    return *reinterpret_cast<unsigned*>(&h);
}

#define ACCM(p, u)                                            \
    fmix2(p##0, p##1, u.x, one); fmix2(p##2, p##3, u.y, one); \
    fmix2(p##4, p##5, u.z, one); fmix2(p##6, p##7, u.w, one)

#define RED2(x) x += __shfl_xor(x, 16); x += __shfl_xor(x, 32)

// ---- zero deg[12288] (12 blocks * 256 * int4 = 49152 B) ----
__global__ __launch_bounds__(256) void clear_ws(int4* __restrict__ p) {
    p[blockIdx.x * 256 + threadIdx.x] = int4{0, 0, 0, 0};
}

// ---- merged: x->f16 + ELL edge scatter (blocks 0..2999) | weight fuse+pack (3000..3127) ----
// Weight layout Wq*: uint4 at (t*256 + c0*2) = { (k2,c0), (k2+1,c0), (k2,c0+1), (k2+1,c0+1) }, k2 = 2t.
__global__ __launch_bounds__(256) void prep_fuse(const float* __restrict__ x,
                                                 unsigned* __restrict__ xbu,
                                                 const int* __restrict__ ei,
                                                 int* __restrict__ deg,
                                                 int* __restrict__ col,
                                                 const float* __restrict__ W1,
                                                 const float* __restrict__ W2,
                                                 const float* __restrict__ Wg,
                                                 const float* __restrict__ b1,
                                                 const float* __restrict__ b2,
                                                 const float* __restrict__ bg,
                                                 unsigned* __restrict__ Wq1,
                                                 unsigned* __restrict__ Wq2,
                                                 unsigned* __restrict__ Wqf1,
                                                 unsigned* __restrict__ Wqf2,
                                                 float* __restrict__ bfused) {
    const int tid = threadIdx.x;
    if (blockIdx.x < 3000) {
        int g = blockIdx.x * 256 + tid;
        if (g < N_NODES * C / 2) {
            unsigned pa = __half_as_ushort(__float2half(x[2 * g]));
            unsigned pb = __half_as_ushort(__float2half(x[2 * g + 1]));
            xbu[g] = pa | (pb << 16);
        }
        if (g < NEDGE) {
            int s = ei[g];
            int t = ei[NEDGE + g];
            int pos = atomicAdd(&deg[s], 1);
            col[(s << 6) + pos] = t;
        }
        return;
    }
    __shared__ __align__(16) float wg1[C];
    __shared__ __align__(16) float wg2[C];
    __shared__ float sb[C];
    __shared__ float l1[C], l2[C], lf1[C], lf2[C];
    const int c = blockIdx.x - 3000;
    const int j = tid;
    if (j < 128) {
        float g1 = Wg[(size_t)j * C + c];
        float g2 = Wg[(size_t)(C + j) * C + c];
        wg1[j] = g1;
        wg2[j] = g2;
        sb[j] = b1[j] * g1 + b2[j] * g2;
    }
    __syncthreads();
    if (j < 128) {
        float s1 = 0.f, s2 = 0.f;
        for (int k = 0; k < C; k += 4) {
            float4 a = *(const float4*)&W1[(size_t)j * C + k];
            float4 b = *(const float4*)&W2[(size_t)j * C + k];
            float4 u = *(const float4*)&wg1[k];
            float4 v = *(const float4*)&wg2[k];
            s1 += a.x * u.x + a.y * u.y + a.z * u.z + a.w * u.w;
            s2 += b.x * v.x + b.y * v.y + b.z * v.z + b.w * v.w;
        }
        l1[j] = W1[(size_t)j * C + c];
        l2[j] = W2[(size_t)j * C + c];
        lf1[j] = s1;
        lf2[j] = s2;
    }
    __syncthreads();
    if (j < 64) {   // j = k-pair index; t = j>>1 groups two k-pairs, u = j&1
        const int t = j >> 1, u = j & 1;
        const int o = t * 256 + c * 2 + u;
        Wq1[o]  = packh2(l1[2 * j], l1[2 * j + 1]);
        Wq2[o]  = packh2(l2[2 * j], l2[2 * j + 1]);
        Wqf1[o] = packh2(lf1[2 * j], lf1[2 * j + 1]);
        Wqf2[o] = packh2(lf2[2 * j], lf2[2 * j + 1]);
    }
    if (j == 0) {
        float s = bg[c];
        for (int k = 0; k < C; ++k) s += sb[k];
        bfused[c] = s;
    }
}

// ---- mark dup edges via O(1) test-and-set bitset + h(dedup, f16) + agg1(f16 packed) ----
// Wave-per-node, zero barriers. Any one duplicate copy stays unmarked (algebra invariant).
__global__ __launch_bounds__(256) void markdup_h(const int* __restrict__ deg,
                                                 int* __restrict__ col,
                                                 const unsigned* __restrict__ xb,
                                                 unsigned* __restrict__ hb,
                                                 unsigned* __restrict__ agg1p) {
    __shared__ unsigned accS[4][BW];  // 6 KB: per-wave dedup bitset
    __shared__ int rows[4][ELL];      // 1 KB
    const int tid = threadIdx.x;
    const int lane = tid & 63, wv = tid >> 6;
    const int i = blockIdx.x * 4 + wv;
    const int rb = i << 6;
    const int d = deg[i];
    unsigned* acc = accS[wv];
    const uint4* xb4 = (const uint4*)xb;
    const float one = 1.0f;

#pragma unroll
    for (int m = 0; m < 6; ++m) acc[lane + (m << 6)] = 0u;

    int c0v = -1;
    if (lane < d) {
        c0v = col[rb + lane];         // fresh from prep: no sign bit
        unsigned bit = 1u << (c0v & 31);
        unsigned old = atomicOr(&acc[c0v >> 5], bit);
        if (old & bit) {              // duplicate: mark (one copy stays unmarked)
            c0v |= 0x80000000;
            col[rb + lane] = c0v;     // visible to next dispatch
        }
    }
    rows[wv][lane] = c0v;

    const int g = lane >> 4, l16 = lane & 15;
    float a0 = 0, a1 = 0, a2 = 0, a3 = 0, a4 = 0, a5 = 0, a6 = 0, a7 = 0;
    float b0 = 0, b1 = 0, b2 = 0, b3 = 0, b4 = 0, b5 = 0, b6 = 0, b7 = 0;
    for (int e = g; e < d; e += 4) {
        int c0 = rows[wv][e];
        int k = c0 & MSK;
        uint4 u = xb4[(unsigned)((k << 4) | l16)];
        ACCM(b, u);
        if (c0 >= 0) { ACCM(a, u); }
    }
    RED2(a0); RED2(a1); RED2(a2); RED2(a3); RED2(a4); RED2(a5); RED2(a6); RED2(a7);
    RED2(b0); RED2(b1); RED2(b2); RED2(b3); RED2(b4); RED2(b5); RED2(b6); RED2(b7);
    if (lane < 16) {
        uint4 hp = {packh2(a0, a1), packh2(a2, a3), packh2(a4, a5), packh2(a6, a7)};
        ((uint4*)hb)[(unsigned)((i << 4) | l16)] = hp;
        uint4 ap = {packh2(b0, b1), packh2(b2, b3), packh2(b4, b5), packh2(b6, b7)};
        ((uint4*)agg1p)[(unsigned)((i << 4) | l16)] = ap;
    }
}

// ---- wave-per-node: union + corrections + agg2(f16 packed) = Adj_bin@h - corr. ----
__global__ __launch_bounds__(256) void twohop_fused(const int* __restrict__ deg,
                                                    const int* __restrict__ col,
                                                    const unsigned* __restrict__ xb,
                                                    const unsigned* __restrict__ hb,
                                                    unsigned* __restrict__ agg2p) {
    __shared__ unsigned accS[4][BW];          // 6 KB: per-wave dedup bitset
    __shared__ int jrowS[4][64];              // 1 KB: per-wave row cache
    __shared__ unsigned short corrS[4][128];  // 1 KB: per-wave corrections
    __shared__ int ncS[4];
    const int tid = threadIdx.x;
    const int lane = tid & 63, wv = tid >> 6;
    const int i = blockIdx.x * 4 + wv;
    unsigned* acc = accS[wv];
    unsigned short* corr = corrS[wv];
    const int rb = i << 6;
    const int d = deg[i];
    const uint4* xb4 = (const uint4*)xb;
    const uint4* hb4 = (const uint4*)hb;
    const float one = 1.0f, neg1 = -1.0f;

#pragma unroll
    for (int m = 0; m < 6; ++m) acc[lane + (m << 6)] = 0u;
    if (lane == 0) ncS[wv] = 0;

    int j = -1, len = 0;
    if (lane < d) {
        j = col[rb + lane];
        if (j >= 0) len = deg[j];
    }
    jrowS[wv][lane] = j;                   // LDS cache: divergence-safe reads later
    const int jb = (j >= 0) ? (j << 6) : 0;
    int p = len;
#pragma unroll
    for (int dd = 1; dd < 64; dd <<= 1) {
        int u = __shfl_up(p, dd);
        if (lane >= dd) p += u;
    }
    const int myPos = p - len;
    const int total = __shfl(p, 63);

    // flattened candidates: UNIFORM trip count; all lanes execute every shfl
    for (int q0 = 0; q0 < total; q0 += 64) {
        const int q = q0 + lane;
        const int qc = (q < total) ? q : (total - 1);
        int lo = 0, hi = d - 1;
#pragma unroll
        for (int it = 0; it < 6; ++it) {
            int mid = (lo + hi + 1) >> 1;
            int sp = __shfl(myPos, mid);
            if (lo < hi) { if (sp <= qc) lo = mid; else hi = mid - 1; }
        }
        const int base = __shfl(jb, lo);
        const int pos0 = __shfl(myPos, lo);
        if (q < total) {
            int t = col[base + (qc - pos0)];
            if (t >= 0) {
                unsigned bit = 1u << (t & 31);
                unsigned old = atomicOr(&acc[t >> 5], bit);
                if (old & bit) {
                    int pc = atomicAdd(&ncS[wv], 1);
                    if (pc < 128) corr[pc] = (unsigned short)t;
                }
            }
        }
    }
    if (lane == 0) {
        if (acc[i >> 5] & (1u << (i & 31))) {
            int pc = atomicAdd(&ncS[wv], 1);
            if (pc < 128) corr[pc] = (unsigned short)i;
        }
    }

    const int g = lane >> 4, l16 = lane & 15;
    float a0 = 0, a1 = 0, a2 = 0, a3 = 0, a4 = 0, a5 = 0, a6 = 0, a7 = 0;
    for (int e = g; e < d; e += 4) {
        int t = jrowS[wv][e];
        if (t >= 0) {
            uint4 u = hb4[(unsigned)((t << 4) | l16)];
            ACCM(a, u);
        }
    }

    {
        int nc = ncS[wv];
        if (nc > 128) nc = 128;
        for (int q = g; q < nc; q += 4) {
            int t = corr[q];
            uint4 u = xb4[(unsigned)((t << 4) | l16)];
            fmix2(a0, a1, u.x, neg1);
            fmix2(a2, a3, u.y, neg1);
            fmix2(a4, a5, u.z, neg1);
            fmix2(a6, a7, u.w, neg1);
        }
    }

    RED2(a0); RED2(a1); RED2(a2); RED2(a3); RED2(a4); RED2(a5); RED2(a6); RED2(a7);
    if (lane < 16) {
        uint4 ap = {packh2(a0, a1), packh2(a2, a3), packh2(a4, a5), packh2(a6, a7)};
        ((uint4*)agg2p)[(unsigned)((i << 4) | l16)] = ap;
    }
}

// ---- single-pass epilogue: 16 rows/block, t-step-2 with uint4 LDS reads ----
__global__ __launch_bounds__(256) void epilogue(const unsigned* __restrict__ agg1p,
                                                const unsigned* __restrict__ agg2p,
                                                const unsigned* __restrict__ Wq1,
                                                const unsigned* __restrict__ Wq2,
                                                const unsigned* __restrict__ Wqf1,
                                                const unsigned* __restrict__ Wqf2,
                                                const float* __restrict__ b1,
                                                const float* __restrict__ b2,
                                                const float* __restrict__ bfused,
                                                float* __restrict__ out) {
    __shared__ unsigned shA[16][64];
    __shared__ unsigned shB[16][64];
    const int r0 = blockIdx.x * 16;
    const int tid = threadIdx.x;
    const int c0 = (tid & 63) * 2;
    const int rg = (tid >> 6) * 4;

    {   // 16 rows x 16 uint4 = 256: one per thread, straight copy (agg already f16)
        const int r = tid >> 4, q4 = tid & 15;
        ((uint4*)shA[r])[q4] = ((const uint4*)agg1p)[(unsigned)(((r0 + r) << 4) | q4)];
        ((uint4*)shB[r])[q4] = ((const uint4*)agg2p)[(unsigned)(((r0 + r) << 4) | q4)];
    }
    __syncthreads();

    float z1v[4][2] = {}, z2v[4][2] = {}, gv[4][2] = {};
    const int wbase = c0 * 2;
    for (int t = 0; t < 32; t += 2) {   // two t's per iteration; b128 LDS reads
        const int o0 = t * 256 + wbase, o1 = o0 + 256;
        uint4 W1a = *(const uint4*)&Wq1[o0], W1b = *(const uint4*)&Wq1[o1];
        uint4 W2a = *(const uint4*)&Wq2[o0], W2b = *(const uint4*)&Wq2[o1];
        uint4 F1a = *(const uint4*)&Wqf1[o0], F1b = *(const uint4*)&Wqf1[o1];
        uint4 F2a = *(const uint4*)&Wqf2[o0], F2b = *(const uint4*)&Wqf2[o1];
        const int k2 = t * 2;
#pragma unroll
        for (int r = 0; r < 4; ++r) {
            uint4 A = *(const uint4*)&shA[rg + r][k2];   // k-pairs k2..k2+3
            uint4 B = *(const uint4*)&shB[rg + r][k2];
            dot2acc(z1v[r][0], A.x, W1a.x); dot2acc(z1v[r][0], A.y, W1a.y);
            dot2acc(z1v[r][1], A.x, W1a.z); dot2acc(z1v[r][1], A.y, W1a.w);
            dot2acc(z1v[r][0], A.z, W1b.x); dot2acc(z1v[r][0], A.w, W1b.y);
            dot2acc(z1v[r][1], A.z, W1b.z); dot2acc(z1v[r][1], A.w, W1b.w);
            dot2acc(z2v[r][0], B.x, W2a.x); dot2acc(z2v[r][0], B.y, W2a.y);
            dot2acc(z2v[r][1], B.x, W2a.z); dot2acc(z2v[r][1], B.y, W2a.w);
            dot2acc(z2v[r][0], B.z, W2b.x); dot2acc(z2v[r][0], B.w, W2b.y);
            dot2acc(z2v[r][1], B.z, W2b.z); dot2acc(z2v[r][1], B.w, W2b.w);
            dot2acc(gv[r][0], A.x, F1a.x);  dot2acc(gv[r][0], A.y, F1a.y);
            dot2acc(gv[r][1], A.x, F1a.z);  dot2acc(gv[r][1], A.y, F1a.w);
            dot2acc(gv[r][0], A.z, F1b.x);  dot2acc(gv[r][0], A.w, F1b.y);
            dot2acc(gv[r][1], A.z, F1b.z);  dot2acc(gv[r][1], A.w, F1b.w);
            dot2acc(gv[r][0], B.x, F2a.x);  dot2acc(gv[r][0], B.y, F2a.y);
            dot2acc(gv[r][1], B.x, F2a.z);  dot2acc(gv[r][1], B.y, F2a.w);
            dot2acc(gv[r][0], B.z, F2b.x);  dot2acc(gv[r][0], B.w, F2b.y);
            dot2acc(gv[r][1], B.z, F2b.z);  dot2acc(gv[r][1], B.w, F2b.w);
        }
    }
    const float2 b1v = *(const float2*)&b1[c0];
    const float2 b2v = *(const float2*)&b2[c0];
    const float2 bfv = *(const float2*)&bfused[c0];
#pragma unroll
    for (int r = 0; r < 4; ++r) {
        float g0 = 1.f / (1.f + expf(-(gv[r][0] + bfv.x)));
        float g1 = 1.f / (1.f + expf(-(gv[r][1] + bfv.y)));
        float2 res;
        res.x = g0 * (z1v[r][0] + b1v.x) + (1.f - g0) * (z2v[r][0] + b2v.x);
        res.y = g1 * (z1v[r][1] + b1v.y) + (1.f - g1) * (z2v[r][1] + b2v.y);
        *(float2*)&out[(size_t)(r0 + rg + r) * C + c0] = res;
    }
}

extern "C" void kernel_launch(void* const* d_in, const int* in_sizes, int n_in,
                              void* d_out, int out_size, void* d_ws, size_t ws_size,
                              hipStream_t stream) {
    const float* x  = (const float*)d_in[0];
    const int*   ei = (const int*)d_in[1];
    const float* W1 = (const float*)d_in[2];
    const float* b1 = (const float*)d_in[3];
    const float* W2 = (const float*)d_in[4];
    const float* b2 = (const float*)d_in[5];
    const float* Wg = (const float*)d_in[6];
    const float* bg = (const float*)d_in[7];
    float* out = (float*)d_out;

    char* ws = (char*)d_ws;
    size_t o = 0;
    auto alloc = [&](size_t bytes) { char* p = ws + o; o = (o + bytes + 255) & ~(size_t)255; return p; };
    int* col      = (int*)alloc((size_t)N_NODES * ELL * 4);       // 3 MB ELL
    int* deg      = (int*)alloc((size_t)12288 * 4);               // cleared region (49152 B)
    unsigned* xb  = (unsigned*)alloc((size_t)N_NODES * C * 2);    // f16 x
    unsigned* hb  = (unsigned*)alloc((size_t)N_NODES * C * 2);    // f16 h = Adj_bin@x
    unsigned* agg1p = (unsigned*)alloc((size_t)N_NODES * C * 2);  // f16 packed agg1
    unsigned* agg2p = (unsigned*)alloc((size_t)N_NODES * C * 2);  // f16 packed agg2
    unsigned* Wq1  = (unsigned*)alloc((size_t)(C / 2) * C * 4);
    unsigned* Wq2  = (unsigned*)alloc((size_t)(C / 2) * C * 4);
    unsigned* Wqf1 = (unsigned*)alloc((size_t)(C / 2) * C * 4);
    unsigned* Wqf2 = (unsigned*)alloc((size_t)(C / 2) * C * 4);
    float* bfused  = (float*)alloc((size_t)C * 4);
    // total ~15.7 MB (proven safe)

    clear_ws<<<12, 256, 0, stream>>>((int4*)deg);
    prep_fuse<<<3128, 256, 0, stream>>>(x, xb, ei, deg, col, W1, W2, Wg, b1, b2, bg,
                                        Wq1, Wq2, Wqf1, Wqf2, bfused);
    markdup_h<<<N_NODES / 4, 256, 0, stream>>>(deg, col, xb, hb, agg1p);
    twohop_fused<<<N_NODES / 4, 256, 0, stream>>>(deg, col, xb, hb, agg2p);
    epilogue<<<N_NODES / 16, 256, 0, stream>>>(agg1p, agg2p, Wq1, Wq2, Wqf1, Wqf2,
                                               b1, b2, bfused, out);
}

// Round 25
// 90.957 us; speedup vs baseline: 1.1145x; 1.0099x over previous
//
#include <hip/hip_runtime.h>
#include <hip/hip_fp16.h>
#include <math.h>

#define N_NODES 12000
#define C 128
#define NEDGE 192000
#define BW 384  // u32 words per dedup bitset (12288 bits >= 12000)
#define MSK 0x7FFFFFFF
#define ELL 64  // ELL row stride; max degree ~45 (Binom(192000,1/12000)), P(>64)~1e-20

// acc_lo += s*(float)f16_lo(u); acc_hi += s*(float)f16_hi(u)  -- one VOP3P each
__device__ __forceinline__ void fmix2(float& lo, float& hi, unsigned u, float s) {
    asm("v_fma_mix_f32 %0, %2, %3, %0 op_sel:[0,0,0] op_sel_hi:[1,0,0]\n\t"
        "v_fma_mix_f32 %1, %2, %3, %1 op_sel:[1,0,0] op_sel_hi:[1,0,0]"
        : "+v"(lo), "+v"(hi)
        : "v"(u), "v"(s));
}

// acc += a.lo*b.lo + a.hi*b.hi  (f16 pairs, f32 accumulate) -- one VOP3P
__device__ __forceinline__ void dot2acc(float& acc, unsigned a, unsigned b) {
    asm("v_dot2_f32_f16 %0, %1, %2, %0" : "+v"(acc) : "v"(a), "v"(b));
}

__device__ __forceinline__ unsigned packh2(float lo, float hi) {
    __half2 h = __floats2half2_rn(lo, hi);
    return *reinterpret_cast<unsigned*>(&h);
}

#define ACCM(p, u)                                            \
    fmix2(p##0, p##1, u.x, one); fmix2(p##2, p##3, u.y, one); \
    fmix2(p##4, p##5, u.z, one); fmix2(p##6, p##7, u.w, one)

#define RED2(x) x += __shfl_xor(x, 16); x += __shfl_xor(x, 32)

// ---- zero deg[12288] (12 blocks * 256 * int4 = 49152 B) ----
__global__ __launch_bounds__(256) void clear_ws(int4* __restrict__ p) {
    p[blockIdx.x * 256 + threadIdx.x] = int4{0, 0, 0, 0};
}

// ---- merged: x->f16 + ELL edge scatter (blocks 0..2999) | weight fuse+pack (3000..3127) ----
// Weight layout Wq*: uint4 at (t*256 + c0*2) = { (k2,c0), (k2+1,c0), (k2,c0+1), (k2+1,c0+1) }, k2 = 2t.
__global__ __launch_bounds__(256) void prep_fuse(const float* __restrict__ x,
                                                 unsigned* __restrict__ xbu,
                                                 const int* __restrict__ ei,
                                                 int* __restrict__ deg,
                                                 int* __restrict__ col,
                                                 const float* __restrict__ W1,
                                                 const float* __restrict__ W2,
                                                 const float* __restrict__ Wg,
                                                 const float* __restrict__ b1,
                                                 const float* __restrict__ b2,
                                                 const float* __restrict__ bg,
                                                 unsigned* __restrict__ Wq1,
                                                 unsigned* __restrict__ Wq2,
                                                 unsigned* __restrict__ Wqf1,
                                                 unsigned* __restrict__ Wqf2,
                                                 float* __restrict__ bfused) {
    const int tid = threadIdx.x;
    if (blockIdx.x < 3000) {
        int g = blockIdx.x * 256 + tid;
        if (g < N_NODES * C / 2) {
            unsigned pa = __half_as_ushort(__float2half(x[2 * g]));
            unsigned pb = __half_as_ushort(__float2half(x[2 * g + 1]));
            xbu[g] = pa | (pb << 16);
        }
        if (g < NEDGE) {
            int s = ei[g];
            int t = ei[NEDGE + g];
            int pos = atomicAdd(&deg[s], 1);
            col[(s << 6) + pos] = t;
        }
        return;
    }
    __shared__ __align__(16) float wg1[C];
    __shared__ __align__(16) float wg2[C];
    __shared__ float sb[C];
    __shared__ float l1[C], l2[C], lf1[C], lf2[C];
    const int c = blockIdx.x - 3000;
    const int j = tid;
    if (j < 128) {
        float g1 = Wg[(size_t)j * C + c];
        float g2 = Wg[(size_t)(C + j) * C + c];
        wg1[j] = g1;
        wg2[j] = g2;
        sb[j] = b1[j] * g1 + b2[j] * g2;
    }
    __syncthreads();
    if (j < 128) {
        float s1 = 0.f, s2 = 0.f;
        for (int k = 0; k < C; k += 4) {
            float4 a = *(const float4*)&W1[(size_t)j * C + k];
            float4 b = *(const float4*)&W2[(size_t)j * C + k];
            float4 u = *(const float4*)&wg1[k];
            float4 v = *(const float4*)&wg2[k];
            s1 += a.x * u.x + a.y * u.y + a.z * u.z + a.w * u.w;
            s2 += b.x * v.x + b.y * v.y + b.z * v.z + b.w * v.w;
        }
        l1[j] = W1[(size_t)j * C + c];
        l2[j] = W2[(size_t)j * C + c];
        lf1[j] = s1;
        lf2[j] = s2;
    }
    __syncthreads();
    if (j < 64) {   // j = k-pair index; t = j>>1 groups two k-pairs, u = j&1
        const int t = j >> 1, u = j & 1;
        const int o = t * 256 + c * 2 + u;
        Wq1[o]  = packh2(l1[2 * j], l1[2 * j + 1]);
        Wq2[o]  = packh2(l2[2 * j], l2[2 * j + 1]);
        Wqf1[o] = packh2(lf1[2 * j], lf1[2 * j + 1]);
        Wqf2[o] = packh2(lf2[2 * j], lf2[2 * j + 1]);
    }
    if (j == 0) {
        float s = bg[c];
        for (int k = 0; k < C; ++k) s += sb[k];
        bfused[c] = s;
    }
}

// ---- mark dup edges via O(1) test-and-set bitset + h(dedup, f16) + agg1(f16 packed) ----
__global__ __launch_bounds__(256) void markdup_h(const int* __restrict__ deg,
                                                 int* __restrict__ col,
                                                 const unsigned* __restrict__ xb,
                                                 unsigned* __restrict__ hb,
                                                 unsigned* __restrict__ agg1p) {
    __shared__ unsigned accS[4][BW];  // 6 KB: per-wave dedup bitset
    __shared__ int rows[4][ELL];      // 1 KB
    const int tid = threadIdx.x;
    const int lane = tid & 63, wv = tid >> 6;
    const int i = blockIdx.x * 4 + wv;
    const int rb = i << 6;
    const int d = deg[i];
    unsigned* acc = accS[wv];
    const uint4* xb4 = (const uint4*)xb;
    const float one = 1.0f;

#pragma unroll
    for (int m = 0; m < 6; ++m) acc[lane + (m << 6)] = 0u;

    int c0v = -1;
    if (lane < d) {
        c0v = col[rb + lane];         // fresh from prep: no sign bit
        unsigned bit = 1u << (c0v & 31);
        unsigned old = atomicOr(&acc[c0v >> 5], bit);
        if (old & bit) {              // duplicate: mark (one copy stays unmarked)
            c0v |= 0x80000000;
            col[rb + lane] = c0v;     // visible to next dispatch
        }
    }
    rows[wv][lane] = c0v;

    const int g = lane >> 4, l16 = lane & 15;
    float a0 = 0, a1 = 0, a2 = 0, a3 = 0, a4 = 0, a5 = 0, a6 = 0, a7 = 0;
    float b0 = 0, b1 = 0, b2 = 0, b3 = 0, b4 = 0, b5 = 0, b6 = 0, b7 = 0;
    for (int e = g; e < d; e += 4) {
        int c0 = rows[wv][e];
        int k = c0 & MSK;
        uint4 u = xb4[(unsigned)((k << 4) | l16)];
        ACCM(b, u);
        if (c0 >= 0) { ACCM(a, u); }
    }
    RED2(a0); RED2(a1); RED2(a2); RED2(a3); RED2(a4); RED2(a5); RED2(a6); RED2(a7);
    RED2(b0); RED2(b1); RED2(b2); RED2(b3); RED2(b4); RED2(b5); RED2(b6); RED2(b7);
    if (lane < 16) {
        uint4 hp = {packh2(a0, a1), packh2(a2, a3), packh2(a4, a5), packh2(a6, a7)};
        ((uint4*)hb)[(unsigned)((i << 4) | l16)] = hp;
        uint4 ap = {packh2(b0, b1), packh2(b2, b3), packh2(b4, b5), packh2(b6, b7)};
        ((uint4*)agg1p)[(unsigned)((i << 4) | l16)] = ap;
    }
}

// ---- wave-per-node: union (16-lane group per neighbor row, coalesced, no search)
//      + corrections + agg2(f16 packed) = Adj_bin@h - corr. Zero barriers. ----
__global__ __launch_bounds__(256) void twohop_fused(const int* __restrict__ deg,
                                                    const int* __restrict__ col,
                                                    const unsigned* __restrict__ xb,
                                                    const unsigned* __restrict__ hb,
                                                    unsigned* __restrict__ agg2p) {
    __shared__ unsigned accS[4][BW];          // 6 KB: per-wave dedup bitset
    __shared__ int jrowS[4][64];              // 1 KB: neighbor ids (for h-gather)
    __shared__ int jlS[4][64];                // 1 KB: packed (j<<6)|len (for union)
    __shared__ unsigned short corrS[4][128];  // 1 KB: per-wave corrections
    __shared__ int ncS[4];
    const int tid = threadIdx.x;
    const int lane = tid & 63, wv = tid >> 6;
    const int i = blockIdx.x * 4 + wv;
    unsigned* acc = accS[wv];
    unsigned short* corr = corrS[wv];
    const int rb = i << 6;
    const int d = deg[i];
    const uint4* xb4 = (const uint4*)xb;
    const uint4* hb4 = (const uint4*)hb;
    const float one = 1.0f, neg1 = -1.0f;
    const int g = lane >> 4, l16 = lane & 15;

#pragma unroll
    for (int m = 0; m < 6; ++m) acc[lane + (m << 6)] = 0u;
    if (lane == 0) ncS[wv] = 0;

    int j = -1, len = 0;
    if (lane < d) {
        j = col[rb + lane];
        if (j >= 0) len = deg[j];
    }
    jrowS[wv][lane] = j;
    jlS[wv][lane] = (j >= 0) ? ((j << 6) | len) : 0;  // len=0 -> row skipped

    // ---- union: group g walks rows e = g, g+4, ...; coalesced 16-lane col reads ----
    for (int e = g; e < d; e += 4) {
        const int jl = jlS[wv][e];
        const int ln = jl & 63;
        const int jbase = jl & ~63;         // j << 6
        for (int l = l16; l < ln; l += 16) {
            int t = col[jbase + l];
            if (t >= 0) {                   // skip marked entries in j's row
                unsigned bit = 1u << (t & 31);
                unsigned old = atomicOr(&acc[t >> 5], bit);
                if (old & bit) {            // duplicate 2-path: correction
                    int pc = atomicAdd(&ncS[wv], 1);
                    if (pc < 128) corr[pc] = (unsigned short)t;
                }
            }
        }
    }
    if (lane == 0) {
        if (acc[i >> 5] & (1u << (i & 31))) {
            int pc = atomicAdd(&ncS[wv], 1);
            if (pc < 128) corr[pc] = (unsigned short)i;
        }
    }

    // ---- t = Adj_bin @ h: gather f16 h rows over unmarked entries ----
    float a0 = 0, a1 = 0, a2 = 0, a3 = 0, a4 = 0, a5 = 0, a6 = 0, a7 = 0;
    for (int e = g; e < d; e += 4) {
        int t = jrowS[wv][e];
        if (t >= 0) {
            uint4 u = hb4[(unsigned)((t << 4) | l16)];
            ACCM(a, u);
        }
    }

    // ---- corrections: subtract x_t for each extra 2-path occurrence ----
    {
        int nc = ncS[wv];
        if (nc > 128) nc = 128;
        for (int q = g; q < nc; q += 4) {
            int t = corr[q];
            uint4 u = xb4[(unsigned)((t << 4) | l16)];
            fmix2(a0, a1, u.x, neg1);
            fmix2(a2, a3, u.y, neg1);
            fmix2(a4, a5, u.z, neg1);
            fmix2(a6, a7, u.w, neg1);
        }
    }

    RED2(a0); RED2(a1); RED2(a2); RED2(a3); RED2(a4); RED2(a5); RED2(a6); RED2(a7);
    if (lane < 16) {
        uint4 ap = {packh2(a0, a1), packh2(a2, a3), packh2(a4, a5), packh2(a6, a7)};
        ((uint4*)agg2p)[(unsigned)((i << 4) | l16)] = ap;
    }
}

// ---- single-pass epilogue: 16 rows/block, t-step-2 with uint4 LDS reads ----
__global__ __launch_bounds__(256) void epilogue(const unsigned* __restrict__ agg1p,
                                                const unsigned* __restrict__ agg2p,
                                                const unsigned* __restrict__ Wq1,
                                                const unsigned* __restrict__ Wq2,
                                                const unsigned* __restrict__ Wqf1,
                                                const unsigned* __restrict__ Wqf2,
                                                const float* __restrict__ b1,
                                                const float* __restrict__ b2,
                                                const float* __restrict__ bfused,
                                                float* __restrict__ out) {
    __shared__ unsigned shA[16][64];
    __shared__ unsigned shB[16][64];
    const int r0 = blockIdx.x * 16;
    const int tid = threadIdx.x;
    const int c0 = (tid & 63) * 2;
    const int rg = (tid >> 6) * 4;

    {   // 16 rows x 16 uint4 = 256: one per thread, straight copy (agg already f16)
        const int r = tid >> 4, q4 = tid & 15;
        ((uint4*)shA[r])[q4] = ((const uint4*)agg1p)[(unsigned)(((r0 + r) << 4) | q4)];
        ((uint4*)shB[r])[q4] = ((const uint4*)agg2p)[(unsigned)(((r0 + r) << 4) | q4)];
    }
    __syncthreads();

    float z1v[4][2] = {}, z2v[4][2] = {}, gv[4][2] = {};
    const int wbase = c0 * 2;
    for (int t = 0; t < 32; t += 2) {   // two t's per iteration; b128 LDS reads
        const int o0 = t * 256 + wbase, o1 = o0 + 256;
        uint4 W1a = *(const uint4*)&Wq1[o0], W1b = *(const uint4*)&Wq1[o1];
        uint4 W2a = *(const uint4*)&Wq2[o0], W2b = *(const uint4*)&Wq2[o1];
        uint4 F1a = *(const uint4*)&Wqf1[o0], F1b = *(const uint4*)&Wqf1[o1];
        uint4 F2a = *(const uint4*)&Wqf2[o0], F2b = *(const uint4*)&Wqf2[o1];
        const int k2 = t * 2;
#pragma unroll
        for (int r = 0; r < 4; ++r) {
            uint4 A = *(const uint4*)&shA[rg + r][k2];   // k-pairs k2..k2+3
            uint4 B = *(const uint4*)&shB[rg + r][k2];
            dot2acc(z1v[r][0], A.x, W1a.x); dot2acc(z1v[r][0], A.y, W1a.y);
            dot2acc(z1v[r][1], A.x, W1a.z); dot2acc(z1v[r][1], A.y, W1a.w);
            dot2acc(z1v[r][0], A.z, W1b.x); dot2acc(z1v[r][0], A.w, W1b.y);
            dot2acc(z1v[r][1], A.z, W1b.z); dot2acc(z1v[r][1], A.w, W1b.w);
            dot2acc(z2v[r][0], B.x, W2a.x); dot2acc(z2v[r][0], B.y, W2a.y);
            dot2acc(z2v[r][1], B.x, W2a.z); dot2acc(z2v[r][1], B.y, W2a.w);
            dot2acc(z2v[r][0], B.z, W2b.x); dot2acc(z2v[r][0], B.w, W2b.y);
            dot2acc(z2v[r][1], B.z, W2b.z); dot2acc(z2v[r][1], B.w, W2b.w);
            dot2acc(gv[r][0], A.x, F1a.x);  dot2acc(gv[r][0], A.y, F1a.y);
            dot2acc(gv[r][1], A.x, F1a.z);  dot2acc(gv[r][1], A.y, F1a.w);
            dot2acc(gv[r][0], A.z, F1b.x);  dot2acc(gv[r][0], A.w, F1b.y);
            dot2acc(gv[r][1], A.z, F1b.z);  dot2acc(gv[r][1], A.w, F1b.w);
            dot2acc(gv[r][0], B.x, F2a.x);  dot2acc(gv[r][0], B.y, F2a.y);
            dot2acc(gv[r][1], B.x, F2a.z);  dot2acc(gv[r][1], B.y, F2a.w);
            dot2acc(gv[r][0], B.z, F2b.x);  dot2acc(gv[r][0], B.w, F2b.y);
            dot2acc(gv[r][1], B.z, F2b.z);  dot2acc(gv[r][1], B.w, F2b.w);
        }
    }
    const float2 b1v = *(const float2*)&b1[c0];
    const float2 b2v = *(const float2*)&b2[c0];
    const float2 bfv = *(const float2*)&bfused[c0];
#pragma unroll
    for (int r = 0; r < 4; ++r) {
        float g0 = 1.f / (1.f + expf(-(gv[r][0] + bfv.x)));
        float g1 = 1.f / (1.f + expf(-(gv[r][1] + bfv.y)));
        float2 res;
        res.x = g0 * (z1v[r][0] + b1v.x) + (1.f - g0) * (z2v[r][0] + b2v.x);
        res.y = g1 * (z1v[r][1] + b1v.y) + (1.f - g1) * (z2v[r][1] + b2v.y);
        *(float2*)&out[(size_t)(r0 + rg + r) * C + c0] = res;
    }
}

extern "C" void kernel_launch(void* const* d_in, const int* in_sizes, int n_in,
                              void* d_out, int out_size, void* d_ws, size_t ws_size,
                              hipStream_t stream) {
    const float* x  = (const float*)d_in[0];
    const int*   ei = (const int*)d_in[1];
    const float* W1 = (const float*)d_in[2];
    const float* b1 = (const float*)d_in[3];
    const float* W2 = (const float*)d_in[4];
    const float* b2 = (const float*)d_in[5];
    const float* Wg = (const float*)d_in[6];
    const float* bg = (const float*)d_in[7];
    float* out = (float*)d_out;

    char* ws = (char*)d_ws;
    size_t o = 0;
    auto alloc = [&](size_t bytes) { char* p = ws + o; o = (o + bytes + 255) & ~(size_t)255; return p; };
    int* col      = (int*)alloc((size_t)N_NODES * ELL * 4);       // 3 MB ELL
    int* deg      = (int*)alloc((size_t)12288 * 4);               // cleared region (49152 B)
    unsigned* xb  = (unsigned*)alloc((size_t)N_NODES * C * 2);    // f16 x
    unsigned* hb  = (unsigned*)alloc((size_t)N_NODES * C * 2);    // f16 h = Adj_bin@x
    unsigned* agg1p = (unsigned*)alloc((size_t)N_NODES * C * 2);  // f16 packed agg1
    unsigned* agg2p = (unsigned*)alloc((size_t)N_NODES * C * 2);  // f16 packed agg2
    unsigned* Wq1  = (unsigned*)alloc((size_t)(C / 2) * C * 4);
    unsigned* Wq2  = (unsigned*)alloc((size_t)(C / 2) * C * 4);
    unsigned* Wqf1 = (unsigned*)alloc((size_t)(C / 2) * C * 4);
    unsigned* Wqf2 = (unsigned*)alloc((size_t)(C / 2) * C * 4);
    float* bfused  = (float*)alloc((size_t)C * 4);
    // total ~15.7 MB (proven safe)

    clear_ws<<<12, 256, 0, stream>>>((int4*)deg);
    prep_fuse<<<3128, 256, 0, stream>>>(x, xb, ei, deg, col, W1, W2, Wg, b1, b2, bg,
                                        Wq1, Wq2, Wqf1, Wqf2, bfused);
    markdup_h<<<N_NODES / 4, 256, 0, stream>>>(deg, col, xb, hb, agg1p);
    twohop_fused<<<N_NODES / 4, 256, 0, stream>>>(deg, col, xb, hb, agg2p);
    epilogue<<<N_NODES / 16, 256, 0, stream>>>(agg1p, agg2p, Wq1, Wq2, Wqf1, Wqf2,
                                               b1, b2, bfused, out);
}

// Round 26
// 88.462 us; speedup vs baseline: 1.1459x; 1.0282x over previous
//
#include <hip/hip_runtime.h>
#include <hip/hip_fp16.h>
#include <math.h>

#define N_NODES 12000
#define C 128
#define NEDGE 192000
#define BW 384  // u32 words per dedup bitset (12288 bits >= 12000)
#define MSK 0x7FFFFFFF
#define ELL 64  // ELL row stride; max degree ~45 (Binom(192000,1/12000)), P(>64)~1e-20

// acc_lo += s*(float)f16_lo(u); acc_hi += s*(float)f16_hi(u)  -- one VOP3P each
__device__ __forceinline__ void fmix2(float& lo, float& hi, unsigned u, float s) {
    asm("v_fma_mix_f32 %0, %2, %3, %0 op_sel:[0,0,0] op_sel_hi:[1,0,0]\n\t"
        "v_fma_mix_f32 %1, %2, %3, %1 op_sel:[1,0,0] op_sel_hi:[1,0,0]"
        : "+v"(lo), "+v"(hi)
        : "v"(u), "v"(s));
}

// acc += a.lo*b.lo + a.hi*b.hi  (f16 pairs, f32 accumulate) -- one VOP3P
__device__ __forceinline__ void dot2acc(float& acc, unsigned a, unsigned b) {
    asm("v_dot2_f32_f16 %0, %1, %2, %0" : "+v"(acc) : "v"(a), "v"(b));
}

__device__ __forceinline__ unsigned packh2(float lo, float hi) {
    __half2 h = __floats2half2_rn(lo, hi);
    return *reinterpret_cast<unsigned*>(&h);
}

#define ACCM(p, u)                                            \
    fmix2(p##0, p##1, u.x, one); fmix2(p##2, p##3, u.y, one); \
    fmix2(p##4, p##5, u.z, one); fmix2(p##6, p##7, u.w, one)

#define RED2(x) x += __shfl_xor(x, 16); x += __shfl_xor(x, 32)

// ---- zero deg[12288] (12 blocks * 256 * int4 = 49152 B) ----
__global__ __launch_bounds__(256) void clear_ws(int4* __restrict__ p) {
    p[blockIdx.x * 256 + threadIdx.x] = int4{0, 0, 0, 0};
}

// ---- merged: x->f16 (float4, blocks 0..1499) + ELL edge scatter (blocks 0..749)
//      | weight fuse+pack (blocks 1500..1627) ----
// Weight layout Wq*: uint4 at (t*256 + c0*2) = { (k2,c0), (k2+1,c0), (k2,c0+1), (k2+1,c0+1) }, k2 = 2t.
__global__ __launch_bounds__(256) void prep_fuse(const float* __restrict__ x,
                                                 unsigned* __restrict__ xbu,
                                                 const int* __restrict__ ei,
                                                 int* __restrict__ deg,
                                                 int* __restrict__ col,
                                                 const float* __restrict__ W1,
                                                 const float* __restrict__ W2,
                                                 const float* __restrict__ Wg,
                                                 const float* __restrict__ b1,
                                                 const float* __restrict__ b2,
                                                 const float* __restrict__ bg,
                                                 unsigned* __restrict__ Wq1,
                                                 unsigned* __restrict__ Wq2,
                                                 unsigned* __restrict__ Wqf1,
                                                 unsigned* __restrict__ Wqf2,
                                                 float* __restrict__ bfused) {
    const int tid = threadIdx.x;
    if (blockIdx.x < 1500) {
        int g = blockIdx.x * 256 + tid;
        if (g < N_NODES * C / 4) {   // 4 floats -> 2 packed f16 pairs per thread
            float4 v = ((const float4*)x)[g];
            uint2 o;
            o.x = packh2(v.x, v.y);
            o.y = packh2(v.z, v.w);
            ((uint2*)xbu)[g] = o;
        }
        if (g < NEDGE) {
            int s = ei[g];
            int t = ei[NEDGE + g];
            int pos = atomicAdd(&deg[s], 1);
            col[(s << 6) + pos] = t;
        }
        return;
    }
    __shared__ __align__(16) float wg1[C];
    __shared__ __align__(16) float wg2[C];
    __shared__ float sb[C];
    __shared__ float l1[C], l2[C], lf1[C], lf2[C];
    const int c = blockIdx.x - 1500;
    const int j = tid;
    if (j < 128) {
        float g1 = Wg[(size_t)j * C + c];
        float g2 = Wg[(size_t)(C + j) * C + c];
        wg1[j] = g1;
        wg2[j] = g2;
        sb[j] = b1[j] * g1 + b2[j] * g2;
    }
    __syncthreads();
    if (j < 128) {
        float s1 = 0.f, s2 = 0.f;
        for (int k = 0; k < C; k += 4) {
            float4 a = *(const float4*)&W1[(size_t)j * C + k];
            float4 b = *(const float4*)&W2[(size_t)j * C + k];
            float4 u = *(const float4*)&wg1[k];
            float4 v = *(const float4*)&wg2[k];
            s1 += a.x * u.x + a.y * u.y + a.z * u.z + a.w * u.w;
            s2 += b.x * v.x + b.y * v.y + b.z * v.z + b.w * v.w;
        }
        l1[j] = W1[(size_t)j * C + c];
        l2[j] = W2[(size_t)j * C + c];
        lf1[j] = s1;
        lf2[j] = s2;
    }
    __syncthreads();
    if (j < 64) {   // j = k-pair index; t = j>>1 groups two k-pairs, u = j&1
        const int t = j >> 1, u = j & 1;
        const int o = t * 256 + c * 2 + u;
        Wq1[o]  = packh2(l1[2 * j], l1[2 * j + 1]);
        Wq2[o]  = packh2(l2[2 * j], l2[2 * j + 1]);
        Wqf1[o] = packh2(lf1[2 * j], lf1[2 * j + 1]);
        Wqf2[o] = packh2(lf2[2 * j], lf2[2 * j + 1]);
    }
    if (j == 0) {
        float s = bg[c];
        for (int k = 0; k < C; ++k) s += sb[k];
        bfused[c] = s;
    }
}

// ---- mark dup edges via O(1) test-and-set bitset + h(dedup, f16) + agg1(f16 packed) ----
__global__ __launch_bounds__(256) void markdup_h(const int* __restrict__ deg,
                                                 int* __restrict__ col,
                                                 const unsigned* __restrict__ xb,
                                                 unsigned* __restrict__ hb,
                                                 unsigned* __restrict__ agg1p) {
    __shared__ unsigned accS[4][BW];  // 6 KB: per-wave dedup bitset
    __shared__ int rows[4][ELL];      // 1 KB
    const int tid = threadIdx.x;
    const int lane = tid & 63, wv = tid >> 6;
    const int i = blockIdx.x * 4 + wv;
    const int rb = i << 6;
    const int d = deg[i];
    unsigned* acc = accS[wv];
    const uint4* xb4 = (const uint4*)xb;
    const float one = 1.0f;

#pragma unroll
    for (int m = 0; m < 6; ++m) acc[lane + (m << 6)] = 0u;

    int c0v = -1;
    if (lane < d) {
        c0v = col[rb + lane];         // fresh from prep: no sign bit
        unsigned bit = 1u << (c0v & 31);
        unsigned old = atomicOr(&acc[c0v >> 5], bit);
        if (old & bit) {              // duplicate: mark (one copy stays unmarked)
            c0v |= 0x80000000;
            col[rb + lane] = c0v;     // visible to next dispatch
        }
    }
    rows[wv][lane] = c0v;

    const int g = lane >> 4, l16 = lane & 15;
    float a0 = 0, a1 = 0, a2 = 0, a3 = 0, a4 = 0, a5 = 0, a6 = 0, a7 = 0;
    float b0 = 0, b1 = 0, b2 = 0, b3 = 0, b4 = 0, b5 = 0, b6 = 0, b7 = 0;
    for (int e = g; e < d; e += 4) {
        int c0 = rows[wv][e];
        int k = c0 & MSK;
        uint4 u = xb4[(unsigned)((k << 4) | l16)];
        ACCM(b, u);
        if (c0 >= 0) { ACCM(a, u); }
    }
    RED2(a0); RED2(a1); RED2(a2); RED2(a3); RED2(a4); RED2(a5); RED2(a6); RED2(a7);
    RED2(b0); RED2(b1); RED2(b2); RED2(b3); RED2(b4); RED2(b5); RED2(b6); RED2(b7);
    if (lane < 16) {
        uint4 hp = {packh2(a0, a1), packh2(a2, a3), packh2(a4, a5), packh2(a6, a7)};
        ((uint4*)hb)[(unsigned)((i << 4) | l16)] = hp;
        uint4 ap = {packh2(b0, b1), packh2(b2, b3), packh2(b4, b5), packh2(b6, b7)};
        ((uint4*)agg1p)[(unsigned)((i << 4) | l16)] = ap;
    }
}

// ---- wave-per-node: union (16-lane group per neighbor row, coalesced, no search)
//      + corrections + agg2(f16 packed) = Adj_bin@h - corr. Zero barriers. ----
__global__ __launch_bounds__(256) void twohop_fused(const int* __restrict__ deg,
                                                    const int* __restrict__ col,
                                                    const unsigned* __restrict__ xb,
                                                    const unsigned* __restrict__ hb,
                                                    unsigned* __restrict__ agg2p) {
    __shared__ unsigned accS[4][BW];          // 6 KB: per-wave dedup bitset
    __shared__ int jrowS[4][64];              // 1 KB: neighbor ids (for h-gather)
    __shared__ int jlS[4][64];                // 1 KB: packed (j<<6)|len (for union)
    __shared__ unsigned short corrS[4][128];  // 1 KB: per-wave corrections
    __shared__ int ncS[4];
    const int tid = threadIdx.x;
    const int lane = tid & 63, wv = tid >> 6;
    const int i = blockIdx.x * 4 + wv;
    unsigned* acc = accS[wv];
    unsigned short* corr = corrS[wv];
    const int rb = i << 6;
    const int d = deg[i];
    const uint4* xb4 = (const uint4*)xb;
    const uint4* hb4 = (const uint4*)hb;
    const float one = 1.0f, neg1 = -1.0f;
    const int g = lane >> 4, l16 = lane & 15;

#pragma unroll
    for (int m = 0; m < 6; ++m) acc[lane + (m << 6)] = 0u;
    if (lane == 0) ncS[wv] = 0;

    int j = -1, len = 0;
    if (lane < d) {
        j = col[rb + lane];
        if (j >= 0) len = deg[j];
    }
    jrowS[wv][lane] = j;
    jlS[wv][lane] = (j >= 0) ? ((j << 6) | len) : 0;  // len=0 -> row skipped

    // ---- union: group g walks rows e = g, g+4, ...; coalesced 16-lane col reads ----
    for (int e = g; e < d; e += 4) {
        const int jl = jlS[wv][e];
        const int ln = jl & 63;
        const int jbase = jl & ~63;         // j << 6
        for (int l = l16; l < ln; l += 16) {
            int t = col[jbase + l];
            if (t >= 0) {                   // skip marked entries in j's row
                unsigned bit = 1u << (t & 31);
                unsigned old = atomicOr(&acc[t >> 5], bit);
                if (old & bit) {            // duplicate 2-path: correction
                    int pc = atomicAdd(&ncS[wv], 1);
                    if (pc < 128) corr[pc] = (unsigned short)t;
                }
            }
        }
    }
    if (lane == 0) {
        if (acc[i >> 5] & (1u << (i & 31))) {
            int pc = atomicAdd(&ncS[wv], 1);
            if (pc < 128) corr[pc] = (unsigned short)i;
        }
    }

    // ---- t = Adj_bin @ h: gather f16 h rows over unmarked entries ----
    float a0 = 0, a1 = 0, a2 = 0, a3 = 0, a4 = 0, a5 = 0, a6 = 0, a7 = 0;
    for (int e = g; e < d; e += 4) {
        int t = jrowS[wv][e];
        if (t >= 0) {
            uint4 u = hb4[(unsigned)((t << 4) | l16)];
            ACCM(a, u);
        }
    }

    // ---- corrections: subtract x_t for each extra 2-path occurrence ----
    {
        int nc = ncS[wv];
        if (nc > 128) nc = 128;
        for (int q = g; q < nc; q += 4) {
            int t = corr[q];
            uint4 u = xb4[(unsigned)((t << 4) | l16)];
            fmix2(a0, a1, u.x, neg1);
            fmix2(a2, a3, u.y, neg1);
            fmix2(a4, a5, u.z, neg1);
            fmix2(a6, a7, u.w, neg1);
        }
    }

    RED2(a0); RED2(a1); RED2(a2); RED2(a3); RED2(a4); RED2(a5); RED2(a6); RED2(a7);
    if (lane < 16) {
        uint4 ap = {packh2(a0, a1), packh2(a2, a3), packh2(a4, a5), packh2(a6, a7)};
        ((uint4*)agg2p)[(unsigned)((i << 4) | l16)] = ap;
    }
}

// ---- single-pass epilogue: 16 rows/block, t-step-2 with uint4 LDS reads ----
__global__ __launch_bounds__(256) void epilogue(const unsigned* __restrict__ agg1p,
                                                const unsigned* __restrict__ agg2p,
                                                const unsigned* __restrict__ Wq1,
                                                const unsigned* __restrict__ Wq2,
                                                const unsigned* __restrict__ Wqf1,
                                                const unsigned* __restrict__ Wqf2,
                                                const float* __restrict__ b1,
                                                const float* __restrict__ b2,
                                                const float* __restrict__ bfused,
                                                float* __restrict__ out) {
    __shared__ unsigned shA[16][64];
    __shared__ unsigned shB[16][64];
    const int r0 = blockIdx.x * 16;
    const int tid = threadIdx.x;
    const int c0 = (tid & 63) * 2;
    const int rg = (tid >> 6) * 4;

    {   // 16 rows x 16 uint4 = 256: one per thread, straight copy (agg already f16)
        const int r = tid >> 4, q4 = tid & 15;
        ((uint4*)shA[r])[q4] = ((const uint4*)agg1p)[(unsigned)(((r0 + r) << 4) | q4)];
        ((uint4*)shB[r])[q4] = ((const uint4*)agg2p)[(unsigned)(((r0 + r) << 4) | q4)];
    }
    __syncthreads();

    float z1v[4][2] = {}, z2v[4][2] = {}, gv[4][2] = {};
    const int wbase = c0 * 2;
    for (int t = 0; t < 32; t += 2) {   // two t's per iteration; b128 LDS reads
        const int o0 = t * 256 + wbase, o1 = o0 + 256;
        uint4 W1a = *(const uint4*)&Wq1[o0], W1b = *(const uint4*)&Wq1[o1];
        uint4 W2a = *(const uint4*)&Wq2[o0], W2b = *(const uint4*)&Wq2[o1];
        uint4 F1a = *(const uint4*)&Wqf1[o0], F1b = *(const uint4*)&Wqf1[o1];
        uint4 F2a = *(const uint4*)&Wqf2[o0], F2b = *(const uint4*)&Wqf2[o1];
        const int k2 = t * 2;
#pragma unroll
        for (int r = 0; r < 4; ++r) {
            uint4 A = *(const uint4*)&shA[rg + r][k2];   // k-pairs k2..k2+3
            uint4 B = *(const uint4*)&shB[rg + r][k2];
            dot2acc(z1v[r][0], A.x, W1a.x); dot2acc(z1v[r][0], A.y, W1a.y);
            dot2acc(z1v[r][1], A.x, W1a.z); dot2acc(z1v[r][1], A.y, W1a.w);
            dot2acc(z1v[r][0], A.z, W1b.x); dot2acc(z1v[r][0], A.w, W1b.y);
            dot2acc(z1v[r][1], A.z, W1b.z); dot2acc(z1v[r][1], A.w, W1b.w);
            dot2acc(z2v[r][0], B.x, W2a.x); dot2acc(z2v[r][0], B.y, W2a.y);
            dot2acc(z2v[r][1], B.x, W2a.z); dot2acc(z2v[r][1], B.y, W2a.w);
            dot2acc(z2v[r][0], B.z, W2b.x); dot2acc(z2v[r][0], B.w, W2b.y);
            dot2acc(z2v[r][1], B.z, W2b.z); dot2acc(z2v[r][1], B.w, W2b.w);
            dot2acc(gv[r][0], A.x, F1a.x);  dot2acc(gv[r][0], A.y, F1a.y);
            dot2acc(gv[r][1], A.x, F1a.z);  dot2acc(gv[r][1], A.y, F1a.w);
            dot2acc(gv[r][0], A.z, F1b.x);  dot2acc(gv[r][0], A.w, F1b.y);
            dot2acc(gv[r][1], A.z, F1b.z);  dot2acc(gv[r][1], A.w, F1b.w);
            dot2acc(gv[r][0], B.x, F2a.x);  dot2acc(gv[r][0], B.y, F2a.y);
            dot2acc(gv[r][1], B.x, F2a.z);  dot2acc(gv[r][1], B.y, F2a.w);
            dot2acc(gv[r][0], B.z, F2b.x);  dot2acc(gv[r][0], B.w, F2b.y);
            dot2acc(gv[r][1], B.z, F2b.z);  dot2acc(gv[r][1], B.w, F2b.w);
        }
    }
    const float2 b1v = *(const float2*)&b1[c0];
    const float2 b2v = *(const float2*)&b2[c0];
    const float2 bfv = *(const float2*)&bfused[c0];
#pragma unroll
    for (int r = 0; r < 4; ++r) {
        float g0 = 1.f / (1.f + expf(-(gv[r][0] + bfv.x)));
        float g1 = 1.f / (1.f + expf(-(gv[r][1] + bfv.y)));
        float2 res;
        res.x = g0 * (z1v[r][0] + b1v.x) + (1.f - g0) * (z2v[r][0] + b2v.x);
        res.y = g1 * (z1v[r][1] + b1v.y) + (1.f - g1) * (z2v[r][1] + b2v.y);
        *(float2*)&out[(size_t)(r0 + rg + r) * C + c0] = res;
    }
}

extern "C" void kernel_launch(void* const* d_in, const int* in_sizes, int n_in,
                              void* d_out, int out_size, void* d_ws, size_t ws_size,
                              hipStream_t stream) {
    const float* x  = (const float*)d_in[0];
    const int*   ei = (const int*)d_in[1];
    const float* W1 = (const float*)d_in[2];
    const float* b1 = (const float*)d_in[3];
    const float* W2 = (const float*)d_in[4];
    const float* b2 = (const float*)d_in[5];
    const float* Wg = (const float*)d_in[6];
    const float* bg = (const float*)d_in[7];
    float* out = (float*)d_out;

    char* ws = (char*)d_ws;
    size_t o = 0;
    auto alloc = [&](size_t bytes) { char* p = ws + o; o = (o + bytes + 255) & ~(size_t)255; return p; };
    int* col      = (int*)alloc((size_t)N_NODES * ELL * 4);       // 3 MB ELL
    int* deg      = (int*)alloc((size_t)12288 * 4);               // cleared region (49152 B)
    unsigned* xb  = (unsigned*)alloc((size_t)N_NODES * C * 2);    // f16 x
    unsigned* hb  = (unsigned*)alloc((size_t)N_NODES * C * 2);    // f16 h = Adj_bin@x
    unsigned* agg1p = (unsigned*)alloc((size_t)N_NODES * C * 2);  // f16 packed agg1
    unsigned* agg2p = (unsigned*)alloc((size_t)N_NODES * C * 2);  // f16 packed agg2
    unsigned* Wq1  = (unsigned*)alloc((size_t)(C / 2) * C * 4);
    unsigned* Wq2  = (unsigned*)alloc((size_t)(C / 2) * C * 4);
    unsigned* Wqf1 = (unsigned*)alloc((size_t)(C / 2) * C * 4);
    unsigned* Wqf2 = (unsigned*)alloc((size_t)(C / 2) * C * 4);
    float* bfused  = (float*)alloc((size_t)C * 4);
    // total ~15.7 MB (proven safe)

    clear_ws<<<12, 256, 0, stream>>>((int4*)deg);
    prep_fuse<<<1628, 256, 0, stream>>>(x, xb, ei, deg, col, W1, W2, Wg, b1, b2, bg,
                                        Wq1, Wq2, Wqf1, Wqf2, bfused);
    markdup_h<<<N_NODES / 4, 256, 0, stream>>>(deg, col, xb, hb, agg1p);
    twohop_fused<<<N_NODES / 4, 256, 0, stream>>>(deg, col, xb, hb, agg2p);
    epilogue<<<N_NODES / 16, 256, 0, stream>>>(agg1p, agg2p, Wq1, Wq2, Wqf1, Wqf2,
                                               b1, b2, bfused, out);
}

// Round 27
// 85.525 us; speedup vs baseline: 1.1853x; 1.0343x over previous
//
#include <hip/hip_runtime.h>
#include <hip/hip_fp16.h>
#include <math.h>

#define N_NODES 12000
#define C 128
#define NEDGE 192000
#define BW 384  // u32 words per dedup bitset (12288 bits >= 12000)
#define MSK 0x7FFFFFFF
#define ELL 64  // ELL row stride; max degree ~45 (Binom(192000,1/12000)), P(>64)~1e-20

// acc_lo += s*(float)f16_lo(u); acc_hi += s*(float)f16_hi(u)  -- one VOP3P each
__device__ __forceinline__ void fmix2(float& lo, float& hi, unsigned u, float s) {
    asm("v_fma_mix_f32 %0, %2, %3, %0 op_sel:[0,0,0] op_sel_hi:[1,0,0]\n\t"
        "v_fma_mix_f32 %1, %2, %3, %1 op_sel:[1,0,0] op_sel_hi:[1,0,0]"
        : "+v"(lo), "+v"(hi)
        : "v"(u), "v"(s));
}

// acc += a.lo*b.lo + a.hi*b.hi  (f16 pairs, f32 accumulate) -- one VOP3P
__device__ __forceinline__ void dot2acc(float& acc, unsigned a, unsigned b) {
    asm("v_dot2_f32_f16 %0, %1, %2, %0" : "+v"(acc) : "v"(a), "v"(b));
}

__device__ __forceinline__ unsigned packh2(float lo, float hi) {
    __half2 h = __floats2half2_rn(lo, hi);
    return *reinterpret_cast<unsigned*>(&h);
}

#define ACCM(p, u)                                            \
    fmix2(p##0, p##1, u.x, one); fmix2(p##2, p##3, u.y, one); \
    fmix2(p##4, p##5, u.z, one); fmix2(p##6, p##7, u.w, one)

#define RED2(x) x += __shfl_xor(x, 16); x += __shfl_xor(x, 32)

// ---- zero deg[12288] (12 blocks * 256 * int4 = 49152 B) ----
__global__ __launch_bounds__(256) void clear_ws(int4* __restrict__ p) {
    p[blockIdx.x * 256 + threadIdx.x] = int4{0, 0, 0, 0};
}

// ---- merged: x->f16 (float4, blocks 0..1499) + ELL edge scatter (blocks 0..749)
//      | weight fuse+pack (blocks 1500..1627) ----
// Weight layout Wq*: uint4 at (t*256 + c0*2) = { (k2,c0), (k2+1,c0), (k2,c0+1), (k2+1,c0+1) }, k2 = 2t.
__global__ __launch_bounds__(256) void prep_fuse(const float* __restrict__ x,
                                                 unsigned* __restrict__ xbu,
                                                 const int* __restrict__ ei,
                                                 int* __restrict__ deg,
                                                 int* __restrict__ col,
                                                 const float* __restrict__ W1,
                                                 const float* __restrict__ W2,
                                                 const float* __restrict__ Wg,
                                                 const float* __restrict__ b1,
                                                 const float* __restrict__ b2,
                                                 const float* __restrict__ bg,
                                                 unsigned* __restrict__ Wq1,
                                                 unsigned* __restrict__ Wq2,
                                                 unsigned* __restrict__ Wqf1,
                                                 unsigned* __restrict__ Wqf2,
                                                 float* __restrict__ bfused) {
    const int tid = threadIdx.x;
    if (blockIdx.x < 1500) {
        int g = blockIdx.x * 256 + tid;
        if (g < N_NODES * C / 4) {   // 4 floats -> 2 packed f16 pairs per thread
            float4 v = ((const float4*)x)[g];
            uint2 o;
            o.x = packh2(v.x, v.y);
            o.y = packh2(v.z, v.w);
            ((uint2*)xbu)[g] = o;
        }
        if (g < NEDGE) {
            int s = ei[g];
            int t = ei[NEDGE + g];
            int pos = atomicAdd(&deg[s], 1);
            col[(s << 6) + pos] = t;
        }
        return;
    }
    __shared__ __align__(16) float wg1[C];
    __shared__ __align__(16) float wg2[C];
    __shared__ float sb[C];
    __shared__ float l1[C], l2[C], lf1[C], lf2[C];
    const int c = blockIdx.x - 1500;
    const int j = tid;
    if (j < 128) {
        float g1 = Wg[(size_t)j * C + c];
        float g2 = Wg[(size_t)(C + j) * C + c];
        wg1[j] = g1;
        wg2[j] = g2;
        sb[j] = b1[j] * g1 + b2[j] * g2;
    }
    __syncthreads();
    if (j < 128) {
        float s1 = 0.f, s2 = 0.f;
        for (int k = 0; k < C; k += 4) {
            float4 a = *(const float4*)&W1[(size_t)j * C + k];
            float4 b = *(const float4*)&W2[(size_t)j * C + k];
            float4 u = *(const float4*)&wg1[k];
            float4 v = *(const float4*)&wg2[k];
            s1 += a.x * u.x + a.y * u.y + a.z * u.z + a.w * u.w;
            s2 += b.x * v.x + b.y * v.y + b.z * v.z + b.w * v.w;
        }
        l1[j] = W1[(size_t)j * C + c];
        l2[j] = W2[(size_t)j * C + c];
        lf1[j] = s1;
        lf2[j] = s2;
    }
    __syncthreads();
    if (j < 64) {   // j = k-pair index; t = j>>1 groups two k-pairs, u = j&1
        const int t = j >> 1, u = j & 1;
        const int o = t * 256 + c * 2 + u;
        Wq1[o]  = packh2(l1[2 * j], l1[2 * j + 1]);
        Wq2[o]  = packh2(l2[2 * j], l2[2 * j + 1]);
        Wqf1[o] = packh2(lf1[2 * j], lf1[2 * j + 1]);
        Wqf2[o] = packh2(lf2[2 * j], lf2[2 * j + 1]);
    }
    if (j == 0) {
        float s = bg[c];
        for (int k = 0; k < C; ++k) s += sb[k];
        bfused[c] = s;
    }
}

// ---- mark dup edges via O(1) test-and-set bitset + h(dedup, f16) + agg1(f16 packed) ----
__global__ __launch_bounds__(256) void markdup_h(const int* __restrict__ deg,
                                                 int* __restrict__ col,
                                                 const unsigned* __restrict__ xb,
                                                 unsigned* __restrict__ hb,
                                                 unsigned* __restrict__ agg1p) {
    __shared__ unsigned accS[4][BW];  // 6 KB: per-wave dedup bitset
    __shared__ int rows[4][ELL];      // 1 KB
    const int tid = threadIdx.x;
    const int lane = tid & 63, wv = tid >> 6;
    const int i = blockIdx.x * 4 + wv;
    const int rb = i << 6;
    const int d = deg[i];
    unsigned* acc = accS[wv];
    const uint4* xb4 = (const uint4*)xb;
    const float one = 1.0f;

#pragma unroll
    for (int m = 0; m < 6; ++m) acc[lane + (m << 6)] = 0u;

    int c0v = -1;
    if (lane < d) {
        c0v = col[rb + lane];         // fresh from prep: no sign bit
        unsigned bit = 1u << (c0v & 31);
        unsigned old = atomicOr(&acc[c0v >> 5], bit);
        if (old & bit) {              // duplicate: mark (one copy stays unmarked)
            c0v |= 0x80000000;
            col[rb + lane] = c0v;     // visible to next dispatch
        }
    }
    rows[wv][lane] = c0v;

    const int g = lane >> 4, l16 = lane & 15;
    float a0 = 0, a1 = 0, a2 = 0, a3 = 0, a4 = 0, a5 = 0, a6 = 0, a7 = 0;
    float b0 = 0, b1 = 0, b2 = 0, b3 = 0, b4 = 0, b5 = 0, b6 = 0, b7 = 0;
    for (int e = g; e < d; e += 4) {
        int c0 = rows[wv][e];
        int k = c0 & MSK;
        uint4 u = xb4[(unsigned)((k << 4) | l16)];
        ACCM(b, u);
        if (c0 >= 0) { ACCM(a, u); }
    }
    RED2(a0); RED2(a1); RED2(a2); RED2(a3); RED2(a4); RED2(a5); RED2(a6); RED2(a7);
    RED2(b0); RED2(b1); RED2(b2); RED2(b3); RED2(b4); RED2(b5); RED2(b6); RED2(b7);
    if (lane < 16) {
        uint4 hp = {packh2(a0, a1), packh2(a2, a3), packh2(a4, a5), packh2(a6, a7)};
        ((uint4*)hb)[(unsigned)((i << 4) | l16)] = hp;
        uint4 ap = {packh2(b0, b1), packh2(b2, b3), packh2(b4, b5), packh2(b6, b7)};
        ((uint4*)agg1p)[(unsigned)((i << 4) | l16)] = ap;
    }
}

// ---- wave-per-node: FUSED union + h-gather in one row loop (overlapped latency)
//      + corrections + agg2(f16 packed) = Adj_bin@h - corr. Zero barriers. ----
__global__ __launch_bounds__(256) void twohop_fused(const int* __restrict__ deg,
                                                    const int* __restrict__ col,
                                                    const unsigned* __restrict__ xb,
                                                    const unsigned* __restrict__ hb,
                                                    unsigned* __restrict__ agg2p) {
    __shared__ unsigned accS[4][BW];          // 6 KB: per-wave dedup bitset
    __shared__ int jrowS[4][64];              // 1 KB: neighbor ids (for h-gather)
    __shared__ int jlS[4][64];                // 1 KB: packed (j<<6)|len (for union)
    __shared__ unsigned short corrS[4][128];  // 1 KB: per-wave corrections
    __shared__ int ncS[4];
    const int tid = threadIdx.x;
    const int lane = tid & 63, wv = tid >> 6;
    const int i = blockIdx.x * 4 + wv;
    unsigned* acc = accS[wv];
    unsigned short* corr = corrS[wv];
    const int rb = i << 6;
    const int d = deg[i];
    const uint4* xb4 = (const uint4*)xb;
    const uint4* hb4 = (const uint4*)hb;
    const float one = 1.0f, neg1 = -1.0f;
    const int g = lane >> 4, l16 = lane & 15;

#pragma unroll
    for (int m = 0; m < 6; ++m) acc[lane + (m << 6)] = 0u;
    if (lane == 0) ncS[wv] = 0;

    int j = -1, len = 0;
    if (lane < d) {
        j = col[rb + lane];
        if (j >= 0) len = deg[j];
    }
    jrowS[wv][lane] = j;
    jlS[wv][lane] = (j >= 0) ? ((j << 6) | len) : 0;  // len=0 -> row skipped

    // ---- fused loop: per row e, issue h load (long-latency, independent) then
    //      walk the union of that row (coalesced col reads + LDS test-and-set).
    //      The hb load hides under the union's memory ops. ----
    float a0 = 0, a1 = 0, a2 = 0, a3 = 0, a4 = 0, a5 = 0, a6 = 0, a7 = 0;
    for (int e = g; e < d; e += 4) {
        const int jr = jrowS[wv][e];
        uint4 hu = {0u, 0u, 0u, 0u};
        if (jr >= 0) hu = hb4[(unsigned)((jr << 4) | l16)];   // issue early

        const int jl = jlS[wv][e];
        const int ln = jl & 63;
        const int jbase = jl & ~63;         // j << 6
        for (int l = l16; l < ln; l += 16) {
            int t = col[jbase + l];
            if (t >= 0) {                   // skip marked entries in j's row
                unsigned bit = 1u << (t & 31);
                unsigned old = atomicOr(&acc[t >> 5], bit);
                if (old & bit) {            // duplicate 2-path: correction
                    int pc = atomicAdd(&ncS[wv], 1);
                    if (pc < 128) corr[pc] = (unsigned short)t;
                }
            }
        }
        if (jr >= 0) { ACCM(a, hu); }       // consume after union work
    }
    if (lane == 0) {
        if (acc[i >> 5] & (1u << (i & 31))) {
            int pc = atomicAdd(&ncS[wv], 1);
            if (pc < 128) corr[pc] = (unsigned short)i;
        }
    }

    // ---- corrections: subtract x_t for each extra 2-path occurrence ----
    {
        int nc = ncS[wv];
        if (nc > 128) nc = 128;
        for (int q = g; q < nc; q += 4) {
            int t = corr[q];
            uint4 u = xb4[(unsigned)((t << 4) | l16)];
            fmix2(a0, a1, u.x, neg1);
            fmix2(a2, a3, u.y, neg1);
            fmix2(a4, a5, u.z, neg1);
            fmix2(a6, a7, u.w, neg1);
        }
    }

    RED2(a0); RED2(a1); RED2(a2); RED2(a3); RED2(a4); RED2(a5); RED2(a6); RED2(a7);
    if (lane < 16) {
        uint4 ap = {packh2(a0, a1), packh2(a2, a3), packh2(a4, a5), packh2(a6, a7)};
        ((uint4*)agg2p)[(unsigned)((i << 4) | l16)] = ap;
    }
}

// ---- single-pass epilogue: 16 rows/block, t-step-2 with uint4 LDS reads ----
__global__ __launch_bounds__(256) void epilogue(const unsigned* __restrict__ agg1p,
                                                const unsigned* __restrict__ agg2p,
                                                const unsigned* __restrict__ Wq1,
                                                const unsigned* __restrict__ Wq2,
                                                const unsigned* __restrict__ Wqf1,
                                                const unsigned* __restrict__ Wqf2,
                                                const float* __restrict__ b1,
                                                const float* __restrict__ b2,
                                                const float* __restrict__ bfused,
                                                float* __restrict__ out) {
    __shared__ unsigned shA[16][64];
    __shared__ unsigned shB[16][64];
    const int r0 = blockIdx.x * 16;
    const int tid = threadIdx.x;
    const int c0 = (tid & 63) * 2;
    const int rg = (tid >> 6) * 4;

    {   // 16 rows x 16 uint4 = 256: one per thread, straight copy (agg already f16)
        const int r = tid >> 4, q4 = tid & 15;
        ((uint4*)shA[r])[q4] = ((const uint4*)agg1p)[(unsigned)(((r0 + r) << 4) | q4)];
        ((uint4*)shB[r])[q4] = ((const uint4*)agg2p)[(unsigned)(((r0 + r) << 4) | q4)];
    }
    __syncthreads();

    float z1v[4][2] = {}, z2v[4][2] = {}, gv[4][2] = {};
    const int wbase = c0 * 2;
    for (int t = 0; t < 32; t += 2) {   // two t's per iteration; b128 LDS reads
        const int o0 = t * 256 + wbase, o1 = o0 + 256;
        uint4 W1a = *(const uint4*)&Wq1[o0], W1b = *(const uint4*)&Wq1[o1];
        uint4 W2a = *(const uint4*)&Wq2[o0], W2b = *(const uint4*)&Wq2[o1];
        uint4 F1a = *(const uint4*)&Wqf1[o0], F1b = *(const uint4*)&Wqf1[o1];
        uint4 F2a = *(const uint4*)&Wqf2[o0], F2b = *(const uint4*)&Wqf2[o1];
        const int k2 = t * 2;
#pragma unroll
        for (int r = 0; r < 4; ++r) {
            uint4 A = *(const uint4*)&shA[rg + r][k2];   // k-pairs k2..k2+3
            uint4 B = *(const uint4*)&shB[rg + r][k2];
            dot2acc(z1v[r][0], A.x, W1a.x); dot2acc(z1v[r][0], A.y, W1a.y);
            dot2acc(z1v[r][1], A.x, W1a.z); dot2acc(z1v[r][1], A.y, W1a.w);
            dot2acc(z1v[r][0], A.z, W1b.x); dot2acc(z1v[r][0], A.w, W1b.y);
            dot2acc(z1v[r][1], A.z, W1b.z); dot2acc(z1v[r][1], A.w, W1b.w);
            dot2acc(z2v[r][0], B.x, W2a.x); dot2acc(z2v[r][0], B.y, W2a.y);
            dot2acc(z2v[r][1], B.x, W2a.z); dot2acc(z2v[r][1], B.y, W2a.w);
            dot2acc(z2v[r][0], B.z, W2b.x); dot2acc(z2v[r][0], B.w, W2b.y);
            dot2acc(z2v[r][1], B.z, W2b.z); dot2acc(z2v[r][1], B.w, W2b.w);
            dot2acc(gv[r][0], A.x, F1a.x);  dot2acc(gv[r][0], A.y, F1a.y);
            dot2acc(gv[r][1], A.x, F1a.z);  dot2acc(gv[r][1], A.y, F1a.w);
            dot2acc(gv[r][0], A.z, F1b.x);  dot2acc(gv[r][0], A.w, F1b.y);
            dot2acc(gv[r][1], A.z, F1b.z);  dot2acc(gv[r][1], A.w, F1b.w);
            dot2acc(gv[r][0], B.x, F2a.x);  dot2acc(gv[r][0], B.y, F2a.y);
            dot2acc(gv[r][1], B.x, F2a.z);  dot2acc(gv[r][1], B.y, F2a.w);
            dot2acc(gv[r][0], B.z, F2b.x);  dot2acc(gv[r][0], B.w, F2b.y);
            dot2acc(gv[r][1], B.z, F2b.z);  dot2acc(gv[r][1], B.w, F2b.w);
        }
    }
    const float2 b1v = *(const float2*)&b1[c0];
    const float2 b2v = *(const float2*)&b2[c0];
    const float2 bfv = *(const float2*)&bfused[c0];
#pragma unroll
    for (int r = 0; r < 4; ++r) {
        float g0 = 1.f / (1.f + expf(-(gv[r][0] + bfv.x)));
        float g1 = 1.f / (1.f + expf(-(gv[r][1] + bfv.y)));
        float2 res;
        res.x = g0 * (z1v[r][0] + b1v.x) + (1.f - g0) * (z2v[r][0] + b2v.x);
        res.y = g1 * (z1v[r][1] + b1v.y) + (1.f - g1) * (z2v[r][1] + b2v.y);
        *(float2*)&out[(size_t)(r0 + rg + r) * C + c0] = res;
    }
}

extern "C" void kernel_launch(void* const* d_in, const int* in_sizes, int n_in,
                              void* d_out, int out_size, void* d_ws, size_t ws_size,
                              hipStream_t stream) {
    const float* x  = (const float*)d_in[0];
    const int*   ei = (const int*)d_in[1];
    const float* W1 = (const float*)d_in[2];
    const float* b1 = (const float*)d_in[3];
    const float* W2 = (const float*)d_in[4];
    const float* b2 = (const float*)d_in[5];
    const float* Wg = (const float*)d_in[6];
    const float* bg = (const float*)d_in[7];
    float* out = (float*)d_out;

    char* ws = (char*)d_ws;
    size_t o = 0;
    auto alloc = [&](size_t bytes) { char* p = ws + o; o = (o + bytes + 255) & ~(size_t)255; return p; };
    int* col      = (int*)alloc((size_t)N_NODES * ELL * 4);       // 3 MB ELL
    int* deg      = (int*)alloc((size_t)12288 * 4);               // cleared region (49152 B)
    unsigned* xb  = (unsigned*)alloc((size_t)N_NODES * C * 2);    // f16 x
    unsigned* hb  = (unsigned*)alloc((size_t)N_NODES * C * 2);    // f16 h = Adj_bin@x
    unsigned* agg1p = (unsigned*)alloc((size_t)N_NODES * C * 2);  // f16 packed agg1
    unsigned* agg2p = (unsigned*)alloc((size_t)N_NODES * C * 2);  // f16 packed agg2
    unsigned* Wq1  = (unsigned*)alloc((size_t)(C / 2) * C * 4);
    unsigned* Wq2  = (unsigned*)alloc((size_t)(C / 2) * C * 4);
    unsigned* Wqf1 = (unsigned*)alloc((size_t)(C / 2) * C * 4);
    unsigned* Wqf2 = (unsigned*)alloc((size_t)(C / 2) * C * 4);
    float* bfused  = (float*)alloc((size_t)C * 4);
    // total ~15.7 MB (proven safe)

    clear_ws<<<12, 256, 0, stream>>>((int4*)deg);
    prep_fuse<<<1628, 256, 0, stream>>>(x, xb, ei, deg, col, W1, W2, Wg, b1, b2, bg,
                                        Wq1, Wq2, Wqf1, Wqf2, bfused);
    markdup_h<<<N_NODES / 4, 256, 0, stream>>>(deg, col, xb, hb, agg1p);
    twohop_fused<<<N_NODES / 4, 256, 0, stream>>>(deg, col, xb, hb, agg2p);
    epilogue<<<N_NODES / 16, 256, 0, stream>>>(agg1p, agg2p, Wq1, Wq2, Wqf1, Wqf2,
                                               b1, b2, bfused, out);
}